// Round 3
// baseline (3491.238 us; speedup 1.0000x reference)
//
#include <hip/hip_runtime.h>

#define cB 16
#define cS 512
#define cD 512
#define cL 64
#define cG 8      // blocks per batch
#define cT 1024   // threads per block (16 waves)

// ---------------- workspace layout (bytes) ----------------
constexpr size_t FCOPY   = (size_t)cB * cS * cD * 4;            // 16 MB per F copy
constexpr size_t OFF_F0  = 0;
constexpr size_t OFF_F1  = FCOPY;
constexpr size_t OFF_U   = 2 * FCOPY;                           // D f32
constexpr size_t OFF_V   = OFF_U  + 2048;
constexpr size_t OFF_UA  = OFF_V  + 2048;                       // W1a @ u
constexpr size_t OFF_UB  = OFF_UA + 2048;                       // W1b @ u
constexpr size_t OFF_VA  = OFF_UB + 2048;                       // W1a @ v
constexpr size_t OFF_VB  = OFF_VA + 2048;                       // W1b @ v
constexpr size_t OFF_SC  = OFF_VB + 2048;                       // [c0, cu, cv]
constexpr size_t OFF_SI  = OFF_SC + 64;                         // B*S f32
constexpr size_t OFF_SJ  = OFF_SI + (size_t)cB*cS*4;
constexpr size_t OFF_CLS = OFF_SJ + (size_t)cB*cS*4;
constexpr size_t OFF_ADJ = OFF_CLS+ (size_t)cB*cS*4;            // B*S*8 u64 (row-major)
constexpr size_t OFF_RM  = OFF_ADJ+ (size_t)cB*cS*64;
constexpr size_t OFF_RA  = OFF_RM + (size_t)cB*cS*4;
// prog: per batch 8 counters at 128B stride (no false sharing). 16 KB total.
constexpr size_t OFF_BAR = ((OFF_RA + (size_t)cB*cS*4 + 127) & ~(size_t)127);

// ---------------- DPP max+key reduction helpers (order-independent) ----------
template <int CTRL, int RMASK>
__device__ __forceinline__ void dpp_max_step(float& v, int& k) {
    const float ov = __int_as_float(__builtin_amdgcn_update_dpp(
        (int)0xff800000u, __float_as_int(v), CTRL, RMASK, 0xf, false));
    const int ok = __builtin_amdgcn_update_dpp(
        0x7fffffff, k, CTRL, RMASK, 0xf, false);
    if (ov > v || (ov == v && ok < k)) { v = ov; k = ok; }
}

// full 64-lane (value,key) max; result lands in lane 63
__device__ __forceinline__ void wave_max64(float& v, int& k) {
    dpp_max_step<0x111, 0xf>(v, k);   // row_shr:1
    dpp_max_step<0x112, 0xf>(v, k);   // row_shr:2
    dpp_max_step<0x114, 0xf>(v, k);   // row_shr:4
    dpp_max_step<0x118, 0xf>(v, k);   // row_shr:8
    dpp_max_step<0x142, 0xa>(v, k);   // row_bcast:15 rows 1,3
    dpp_max_step<0x143, 0xc>(v, k);   // row_bcast:31 rows 2,3
}

// x + (lane i+N value); bit-exact replacement of __shfl_down(x,N) for N<=8
// in a down-sweep tree (only prefix lanes feed later steps).
template <int N>
__device__ __forceinline__ float dpp_shl_add(float x) {
    const float o = __int_as_float(__builtin_amdgcn_update_dpp(
        0, __float_as_int(x), 0x100 + N /*row_shl:N*/, 0xf, 0xf, false));
    return x + o;
}

// ---------------- K1: u = W1a@w2, v = W1b@w2, c0 = b1@w2 + b2 ----------------
__global__ void k1_uvc(const float* __restrict__ W1, const float* __restrict__ b1,
                       const float* __restrict__ w2, const float* __restrict__ b2,
                       char* __restrict__ ws) {
    const int t = threadIdx.x;
    const int r = blockIdx.x;
    if (r == 1025) {   // zero progress counters (ws poisoned 0xAA pre-launch)
        unsigned* bar = (unsigned*)(ws + OFF_BAR);
        for (int i = t; i < 4096; i += 256) bar[i] = 0u;
        return;
    }
    __shared__ float rs[256];
    float acc;
    if (r < 1024) {
        const float* row = W1 + (size_t)r * cD;
        acc = row[t] * w2[t] + row[t + 256] * w2[t + 256];
    } else {
        acc = b1[t] * w2[t] + b1[t + 256] * w2[t + 256];
    }
    rs[t] = acc; __syncthreads();
    for (int o = 128; o; o >>= 1) { if (t < o) rs[t] += rs[t + o]; __syncthreads(); }
    if (t == 0) {
        if (r < 512)        ((float*)(ws + OFF_U))[r] = rs[0];
        else if (r < 1024)  ((float*)(ws + OFF_V))[r - 512] = rs[0];
        else                ((float*)(ws + OFF_SC))[0] = rs[0] + b2[0];   // c0
    }
}

// ---------------- K1b: ua/ub/va/vb = W1{a,b} @ {u,v};  cu = b1·u, cv = b1·v --------
__global__ void k1b_proj(const float* __restrict__ W1, const float* __restrict__ b1,
                         char* __restrict__ ws) {
    __shared__ float ru[256], rv[256];
    const int t = threadIdx.x;
    const int k = blockIdx.x;
    const float* U = (const float*)(ws + OFF_U);
    const float* V = (const float*)(ws + OFF_V);
    const float* row = (k < 1024) ? (W1 + (size_t)k * cD) : b1;
    ru[t] = row[t] * U[t] + row[t + 256] * U[t + 256];
    rv[t] = row[t] * V[t] + row[t + 256] * V[t + 256];
    __syncthreads();
    for (int o = 128; o; o >>= 1) {
        if (t < o) { ru[t] += ru[t + o]; rv[t] += rv[t + o]; }
        __syncthreads();
    }
    if (t == 0) {
        if (k < 512)       { ((float*)(ws + OFF_UA))[k] = ru[0]; ((float*)(ws + OFF_VA))[k] = rv[0]; }
        else if (k < 1024) { ((float*)(ws + OFF_UB))[k - 512] = ru[0]; ((float*)(ws + OFF_VB))[k - 512] = rv[0]; }
        else               { ((float*)(ws + OFF_SC))[1] = ru[0]; ((float*)(ws + OFF_SC))[2] = rv[0]; }
    }
}

// ---------------- K2: gather feats into F copy0, si = f@u, sj = f@v ----------------
__global__ void k2_feat(const int* __restrict__ tok, const float* __restrict__ emb,
                        char* __restrict__ ws) {
    __shared__ float ru[256], rv[256];
    const int t = threadIdx.x;
    const int bs = blockIdx.x;
    const float* U = (const float*)(ws + OFF_U);
    const float* V = (const float*)(ws + OFF_V);
    float* F = (float*)(ws + OFF_F0);
    const int tk = tok[bs];
    const float* src = emb + (size_t)tk * cD;
    float* dst = F + (size_t)bs * cD;
    const float e0 = src[t], e1 = src[t + 256];
    dst[t] = e0; dst[t + 256] = e1;
    ru[t] = e0 * U[t] + e1 * U[t + 256];
    rv[t] = e0 * V[t] + e1 * V[t + 256];
    __syncthreads();
    for (int o = 128; o; o >>= 1) {
        if (t < o) { ru[t] += ru[t + o]; rv[t] += rv[t + o]; }
        __syncthreads();
    }
    if (t == 0) {
        ((float*)(ws + OFF_SI))[bs] = ru[0];
        ((float*)(ws + OFF_SJ))[bs] = rv[0];
    }
}

// ---------------- K3: logits argmax -> cls ----------------
__global__ void k3_cls(const float* __restrict__ posW, const float* __restrict__ posb,
                       char* __restrict__ ws) {
    const int t = threadIdx.x;            // one wave
    const int bs = blockIdx.x;
    const float* frow = (const float*)(ws + OFF_F0) + (size_t)bs * cD;
    float acc = posb[t];
    for (int k = 0; k < cD; k++) acc += frow[k] * posW[(size_t)k * cL + t];
    int idx = t;
    for (int off = 32; off; off >>= 1) {
        float ov = __shfl_down(acc, off, 64);
        int   oi = __shfl_down(idx, off, 64);
        if (ov > acc || (ov == acc && oi < idx)) { acc = ov; idx = oi; }
    }
    if (t == 0) ((int*)(ws + OFF_CLS))[bs] = idx;
}

// ---------------- K4: adjacency bitmask + initial per-row max ----------------
__global__ void k4_adj(char* __restrict__ ws) {
    __shared__ float rsv[256]; __shared__ int rsk[256];
    const int t = threadIdx.x;
    const int bs = blockIdx.x;
    const int b = bs >> 9, r = bs & 511;
    const int* cls = (const int*)(ws + OFF_CLS) + (size_t)b * cS;
    const float* SJ = (const float*)(ws + OFF_SJ) + (size_t)b * cS;
    const float sir = ((const float*)(ws + OFF_SI))[bs];
    const float c0 = ((const float*)(ws + OFF_SC))[0];
    unsigned long long* adjrow = (unsigned long long*)(ws + OFF_ADJ) + (size_t)bs * 8;
    const int cr = cls[r];
    float bv = -INFINITY; int bc = 0;
    for (int p = 0; p < 2; p++) {
        const int c = p * 256 + t;
        int dd = c - r; if (dd < 0) dd = -dd;
        const bool allowed = (c != r) && (dd == 1 || cls[c] == cr);
        unsigned long long m = __ballot(allowed);
        if ((t & 63) == 0) adjrow[p * 4 + (t >> 6)] = m;
        if (allowed) {
            float val = sir + SJ[c] + c0;
            if (val > bv || (val == bv && c < bc)) { bv = val; bc = c; }
        }
    }
    rsv[t] = bv; rsk[t] = bc; __syncthreads();
    for (int o = 128; o; o >>= 1) {
        if (t < o) {
            float s2 = rsv[t + o]; int k2 = rsk[t + o];
            if (s2 > rsv[t] || (s2 == rsv[t] && k2 < rsk[t])) { rsv[t] = s2; rsk[t] = k2; }
        }
        __syncthreads();
    }
    if (t == 0) { ((float*)(ws + OFF_RM))[bs] = rsv[0]; ((int*)(ws + OFF_RA))[bs] = rsk[0]; }
}

// ---------------- K5: parser ----------------------------------------------
// vs previous version:
//  * fold phase DELETED: wave0 scans all 512 rmax/rarg directly in phase A
//    (16 conflict-free ds_reads + 8 compares + wave_max64). Same comparator
//    over the same set -> bit-identical argmax. 4 barriers/iter (was 5).
//  * store/drain/publish moved to wave15 IMMEDIATELY after B3 -> the publish
//    other blocks poll on no longer waits behind E+D.
//  * poll skip: wave0 caches minp (proven lower bound of all 8 progress
//    counters, monotone). need <= minp -> no L2 round trip. s_sleep removed.
//  * matvec halves unified (lane = 2m+h), weight pairs kept float2-adjacent
//    for v_pk_fma pairing. FP trees identical (explicit fmaf, same chains).
__global__ void __launch_bounds__(cT, 4)
parse_main(const float* __restrict__ W1, const float* __restrict__ b1,
           char* __restrict__ ws, float* __restrict__ out) {
    const int t  = threadIdx.x;           // 0..1023
    const int b  = blockIdx.x & 15;       // batch (blocks of a batch share an XCD)
    const int g  = blockIdx.x >> 4;       // 0..7
    const int d0 = g * 64;
    const int wf = t >> 6;                // wave id 0..15
    const int ln = t & 63;
    const int wv = wf >> 1;               // k-chunk 0..7
    const int h  = wf & 1;                // half: 0 -> even-pair k, 1 -> odd-pair k

    unsigned long long* F64[2] = {
        (unsigned long long*)(ws + OFF_F0) + (size_t)b * cS * cD / 2,
        (unsigned long long*)(ws + OFF_F1) + (size_t)b * cS * cD / 2 };
    unsigned* prog = (unsigned*)(ws + OFF_BAR) + (size_t)b * 256;   // counters at prog[g*32]
    const float* SCp = (const float*)(ws + OFF_SC);
    const float c0 = SCp[0], cu_c = SCp[1], cv_c = SCp[2];

    // replicated per-block state
    __shared__ unsigned long long AdjL[8 * 512];   // column-major: AdjL[w*512 + r]
    __shared__ float SIl[512], SJl[512], rmax[512];
    __shared__ int   rarg[512];
    __shared__ int   tau[512];                     // last merge step of row r (-1 = never)
    __shared__ unsigned char par[512];             // F-copy parity per row
    __shared__ float rsh[1024];
    __shared__ float ws_si[8], ws_sj[8];
    __shared__ int   s_info;                       // bi | bj<<9 | par_i<<18 | par_j<<19
    __shared__ int   rescanList[516]; __shared__ int nresc;

    // W1 slice: thread (wf,ln) holds 64 k's of chunk wv (h selects pair parity)
    // wreg2[m] = { W1[kbase+4m+2h][d0+ln], W1[kbase+4m+2h+1][d0+ln] }
    const int kbase = wv * 128;
    float2 wreg2[32];
#pragma unroll
    for (int m = 0; m < 32; m++) {
        wreg2[m].x = W1[(size_t)(kbase + 4 * m + 2 * h)     * cD + d0 + ln];
        wreg2[m].y = W1[(size_t)(kbase + 4 * m + 2 * h + 1) * cD + d0 + ln];
    }

    // csi/csj constants (h==0 waves only; they see chunk dims (2ln, 2ln+1))
    const int xk = (wv & 3) * 128 + 2 * ln;
    float cu0 = 0.f, cu1 = 0.f, cv0 = 0.f, cv1 = 0.f;
    if (h == 0) {
        const float* cu_base = (const float*)(ws + ((wv < 4) ? OFF_UA : OFF_UB));
        const float* cvb     = (const float*)(ws + ((wv < 4) ? OFF_VA : OFF_VB));
        cu0 = cu_base[xk]; cu1 = cu_base[xk + 1];
        cv0 = cvb[xk];     cv1 = cvb[xk + 1];
    }

    // replicated init (rows live in t<512)
    if (t < cS) {
        SIl[t]  = ((const float*)(ws + OFF_SI))[b * cS + t];
        SJl[t]  = ((const float*)(ws + OFF_SJ))[b * cS + t];
        rmax[t] = ((const float*)(ws + OFF_RM))[b * cS + t];
        rarg[t] = ((const int*)(ws + OFF_RA))[b * cS + t];
        tau[t]  = -1;
        par[t]  = 0;
        const unsigned long long* AG =
            (const unsigned long long*)(ws + OFF_ADJ) + (size_t)b * cS * 8;
#pragma unroll
        for (int wq = 0; wq < 8; wq++) AdjL[wq * 512 + t] = AG[(size_t)t * 8 + wq];
    }
    float b1v = 0.f;
    if (wf == 15) b1v = b1[d0 + ln];       // storer wave: one output dim per lane
    bool myAlive = true;
    float tot = 0.f;
    int minp = 0;                          // wave0: proven lower bound of prog[*]
    if (t == 0) nresc = 0;
    __syncthreads();   // init barrier (plays B6 for iter 0)

    for (int it = 0; it < cS - 1; ++it) {
        // ---- A: wave0 full argmax over rmax/rarg + dependency poll ----
        if (wf == 0) {
            float bv = -INFINITY; int bk = 0x7fffffff;
#pragma unroll
            for (int k = 0; k < 8; k++) {
                const int r = k * 64 + ln;
                const float v = rmax[r];
                const int key = (r << 9) | (rarg[r] & 511);
                if (v > bv || (v == bv && key < bk)) { bv = v; bk = key; }
            }
            wave_max64(bv, bk);            // result in lane 63
            const int bk63 = __builtin_amdgcn_readlane(bk, 63);
            const int pbi = bk63 >> 9, pbj = bk63 & 511;
            const int ti = tau[pbi], tj = tau[pbj];       // wave-uniform LDS
            const int pi = (int)par[pbi], pj = (int)par[pbj];
            const int need = (ti > tj ? ti : tj) + 1;
            if (need > minp) {
                const unsigned un = (unsigned)need;
                for (;;) {
                    unsigned v = 0xffffffffu;
                    if (ln < 8) v = __hip_atomic_load(prog + ln * 32, __ATOMIC_RELAXED,
                                                      __HIP_MEMORY_SCOPE_AGENT);
                    if (__ballot(v >= un) == ~0ull) break;
                }
                minp = need;
            }
            if (ln == 0) {
                s_info = pbi | (pbj << 9) | (pi << 18) | (pj << 19);
                nresc = 0;
                if (g == 0) {
                    const float bfv = __int_as_float(
                        __builtin_amdgcn_readlane(__float_as_int(bv), 63));
                    tot += bfv;
                    out[16 + b * 1022 + it * 2 + 0] = (float)pbi;
                    out[16 + b * 1022 + it * 2 + 1] = (float)pbj;
                }
            }
        }
        __syncthreads();   // B2
        const int info = s_info;
        const int bi = info & 511, bj = (info >> 9) & 511;

        // ---- C: wave-local load + csi/csj + readlane matvec ----
        const int myrow  = (wv < 4) ? bi : bj;
        const int mypar  = (wv < 4) ? ((info >> 18) & 1) : ((info >> 19) & 1);
        unsigned long long xv = __hip_atomic_load(
            F64[mypar] + (size_t)myrow * 256 + (wv & 3) * 64 + ln,
            __ATOMIC_RELAXED, __HIP_MEMORY_SCOPE_AGENT);
        float2 f2; __builtin_memcpy(&f2, &xv, 8);
        // csi/csj partials (h==0 waves; same tree as before -> bit-exact)
        if (h == 0) {
            float csi = f2.x * cu0 + f2.y * cu1;
            float csj = f2.x * cv0 + f2.y * cv1;
            csi += __shfl_down(csi, 32, 64);  csj += __shfl_down(csj, 32, 64);
            csi += __shfl_down(csi, 16, 64);  csj += __shfl_down(csj, 16, 64);
            csi = dpp_shl_add<8>(csi);  csj = dpp_shl_add<8>(csj);
            csi = dpp_shl_add<4>(csi);  csj = dpp_shl_add<4>(csj);
            csi = dpp_shl_add<2>(csi);  csj = dpp_shl_add<2>(csj);
            csi = dpp_shl_add<1>(csi);  csj = dpp_shl_add<1>(csj);
            if (ln == 0) { ws_si[wv] = csi; ws_sj[wv] = csj; }
        }
        // matvec: lane 2m+h broadcasts its (x,y); h=0 -> a0,a1; h=1 -> a2,a3
        {
            const int ix = __float_as_int(f2.x), iy = __float_as_int(f2.y);
            float aP = 0.f, aQ = 0.f;
#pragma unroll
            for (int m = 0; m < 32; m++) {
                const int lsrc = 2 * m + h;
                const float q0 = __int_as_float(__builtin_amdgcn_readlane(ix, lsrc));
                const float q1 = __int_as_float(__builtin_amdgcn_readlane(iy, lsrc));
                aP = fmaf(wreg2[m].x, q0, aP);
                aQ = fmaf(wreg2[m].y, q1, aQ);
            }
            rsh[t] = aP + aQ;   // h=0: a0+a1, h=1: a2+a3
        }
        __syncthreads();   // B3

        if (wf == 15) {
            // ---- S: gather + store + drain + publish (earliest possible) ----
            const int pari = (info >> 18) & 1;
            float p = b1v;
#pragma unroll
            for (int q = 0; q < 8; q++)
                p += rsh[(2 * q) * 64 + ln] + rsh[(2 * q + 1) * 64 + ln];
            // ((b1+P0)+P1)... with P_q = (a0+a1)+(a2+a3): identical tree
            __hip_atomic_store((float*)F64[pari ^ 1] + (size_t)bi * 512 + d0 + ln, p,
                               __ATOMIC_RELAXED, __HIP_MEMORY_SCOPE_AGENT);
            asm volatile("s_waitcnt vmcnt(0)" ::: "memory");
            if (ln == 0)
                __hip_atomic_store(prog + g * 32, (unsigned)(it + 1), __ATOMIC_RELAXED,
                                   __HIP_MEMORY_SCOPE_AGENT);
        } else if (t < cS) {
            // ---- E: replicated sin/sjn (same tree -> bit-exact) ----
            float su = (ln < 8) ? ws_si[ln] : 0.f;
            float sv = (ln < 8) ? ws_sj[ln] : 0.f;
            su = dpp_shl_add<4>(su);  sv = dpp_shl_add<4>(sv);
            su = dpp_shl_add<2>(su);  sv = dpp_shl_add<2>(sv);
            su = dpp_shl_add<1>(su);  sv = dpp_shl_add<1>(sv);
            const float sn = __int_as_float(
                __builtin_amdgcn_readfirstlane(__float_as_int(su))) + cu_c;
            const float jn = __int_as_float(
                __builtin_amdgcn_readfirstlane(__float_as_int(sv))) + cv_c;

            // ---- D: replicated adjacency + incremental rowmax (LDS only) ----
            const float sjn_ = jn;
            const int wbi = bi >> 6, wbj = bj >> 6;
            const unsigned long long mbi = 1ull << (bi & 63), mbj = 1ull << (bj & 63);
            const int r = t;
            if (r == bj) {
                if (myAlive) { myAlive = false; rmax[t] = -INFINITY; }
            } else if (r == bi) {
                // rebuild own row = (row_bi | row_bj) minus {bi,bj}
#pragma unroll
                for (int wq = 0; wq < 8; wq++) {
                    unsigned long long nw = AdjL[wq * 512 + bi] | AdjL[wq * 512 + bj];
                    if (wq == wbi) nw &= ~mbi;
                    if (wq == wbj) nw &= ~mbj;
                    AdjL[wq * 512 + bi] = nw;
                }
                int slot = atomicAdd(&nresc, 1); rescanList[slot] = bi;
                SIl[bi] = sn; SJl[bi] = jn; par[bi] ^= 1; tau[bi] = it;
            } else if (myAlive) {
                unsigned long long wi = AdjL[wbi * 512 + r];
                unsigned long long wj = (wbj == wbi) ? wi : AdjL[wbj * 512 + r];
                const bool nb = ((wi & mbi) | (wj & mbj)) != 0ull;
                if (wbi == wbj) {
                    AdjL[wbi * 512 + r] = (wi & ~(mbi | mbj)) | (nb ? mbi : 0ull);
                } else {
                    AdjL[wbi * 512 + r] = (wi & ~mbi) | (nb ? mbi : 0ull);
                    AdjL[wbj * 512 + r] = wj & ~mbj;
                }
                const int ra = rarg[t];
                if (ra == bi || ra == bj) {
                    int slot = atomicAdd(&nresc, 1); rescanList[slot] = r;
                } else if (nb) {
                    const float val = SIl[r] + sjn_ + c0;
                    if (val > rmax[t] || (val == rmax[t] && bi < ra)) { rmax[t] = val; rarg[t] = bi; }
                }
            }
        }
        __syncthreads();   // B5

        // ---- wave-parallel rescans (DPP reduce, result lane 63) ----
        const int nr = nresc;
        for (int q = wf; q < nr; q += 16) {
            const int r = rescanList[q];
            const float sir = SIl[r];
            float bv2 = -INFINITY; int bc2 = 0x7fffffff;
#pragma unroll
            for (int k = 0; k < 8; k++) {
                const unsigned long long word = AdjL[k * 512 + r];   // wave-uniform
                if ((word >> ln) & 1ull) {
                    const int c = k * 64 + ln;
                    const float val = sir + SJl[c] + c0;
                    if (val > bv2 || (val == bv2 && c < bc2)) { bv2 = val; bc2 = c; }
                }
            }
            wave_max64(bv2, bc2);
            if (ln == 63) { rmax[r] = bv2; rarg[r] = bc2; }
        }
        __syncthreads();   // B6
    }
    if (g == 0 && t == 0) out[b] = tot;
}

extern "C" void kernel_launch(void* const* d_in, const int* in_sizes, int n_in,
                              void* d_out, int out_size, void* d_ws, size_t ws_size,
                              hipStream_t stream) {
    const int*   token_ids = (const int*)d_in[0];
    const float* vocab_emb = (const float*)d_in[1];
    const float* pos_W     = (const float*)d_in[2];
    const float* pos_b     = (const float*)d_in[3];
    const float* W1        = (const float*)d_in[4];
    const float* b1        = (const float*)d_in[5];
    const float* w2        = (const float*)d_in[6];
    const float* b2        = (const float*)d_in[7];
    float* out = (float*)d_out;
    char*  ws  = (char*)d_ws;

    k1_uvc<<<1026, 256, 0, stream>>>(W1, b1, w2, b2, ws);
    k1b_proj<<<1025, 256, 0, stream>>>(W1, b1, ws);
    k2_feat<<<cB * cS, 256, 0, stream>>>(token_ids, vocab_emb, ws);
    k3_cls<<<cB * cS, 64, 0, stream>>>(pos_W, pos_b, ws);
    k4_adj<<<cB * cS, 256, 0, stream>>>(ws);

    // cooperative launch for the co-residency guarantee (custom waits inside)
    void* args[] = { (void*)&W1, (void*)&b1, (void*)&ws, (void*)&out };
    hipLaunchCooperativeKernel((void*)parse_main, dim3(cB * cG), dim3(cT),
                               args, 0, stream);
}

// Round 4
// 2945.931 us; speedup vs baseline: 1.1851x; 1.1851x over previous
//
#include <hip/hip_runtime.h>

#define cB 16
#define cS 512
#define cD 512
#define cL 64
#define cG 8      // blocks per batch
#define cT 1024   // threads per block (16 waves)

// ---------------- workspace layout (bytes) ----------------
constexpr size_t FCOPY   = (size_t)cB * cS * cD * 4;            // 16 MB per F copy
constexpr size_t OFF_F0  = 0;
constexpr size_t OFF_F1  = FCOPY;
constexpr size_t OFF_U   = 2 * FCOPY;                           // D f32
constexpr size_t OFF_V   = OFF_U  + 2048;
constexpr size_t OFF_UA  = OFF_V  + 2048;                       // W1a @ u
constexpr size_t OFF_UB  = OFF_UA + 2048;                       // W1b @ u
constexpr size_t OFF_VA  = OFF_UB + 2048;                       // W1a @ v
constexpr size_t OFF_VB  = OFF_VA + 2048;                       // W1b @ v
constexpr size_t OFF_SC  = OFF_VB + 2048;                       // [c0, cu, cv]
constexpr size_t OFF_SI  = OFF_SC + 64;                         // B*S f32
constexpr size_t OFF_SJ  = OFF_SI + (size_t)cB*cS*4;
constexpr size_t OFF_CLS = OFF_SJ + (size_t)cB*cS*4;
constexpr size_t OFF_ADJ = OFF_CLS+ (size_t)cB*cS*4;            // B*S*8 u64 (row-major)
constexpr size_t OFF_RM  = OFF_ADJ+ (size_t)cB*cS*64;
constexpr size_t OFF_RA  = OFF_RM + (size_t)cB*cS*4;
// prog: per batch 8 counters at 128B stride (no false sharing). 16 KB total.
constexpr size_t OFF_BAR = ((OFF_RA + (size_t)cB*cS*4 + 127) & ~(size_t)127);

// ---------------- DPP max+key reduction helpers (order-independent) ----------
template <int CTRL, int RMASK>
__device__ __forceinline__ void dpp_max_step(float& v, int& k) {
    const float ov = __int_as_float(__builtin_amdgcn_update_dpp(
        (int)0xff800000u, __float_as_int(v), CTRL, RMASK, 0xf, false));
    const int ok = __builtin_amdgcn_update_dpp(
        0x7fffffff, k, CTRL, RMASK, 0xf, false);
    if (ov > v || (ov == v && ok < k)) { v = ov; k = ok; }
}

// full 64-lane (value,key) max; result lands in lane 63
__device__ __forceinline__ void wave_max64(float& v, int& k) {
    dpp_max_step<0x111, 0xf>(v, k);   // row_shr:1
    dpp_max_step<0x112, 0xf>(v, k);   // row_shr:2
    dpp_max_step<0x114, 0xf>(v, k);   // row_shr:4
    dpp_max_step<0x118, 0xf>(v, k);   // row_shr:8
    dpp_max_step<0x142, 0xa>(v, k);   // row_bcast:15 rows 1,3
    dpp_max_step<0x143, 0xc>(v, k);   // row_bcast:31 rows 2,3
}

// x + (lane i+N value); bit-exact replacement of __shfl_down(x,N) for N<=8
// in a down-sweep tree (only prefix lanes feed later steps).
template <int N>
__device__ __forceinline__ float dpp_shl_add(float x) {
    const float o = __int_as_float(__builtin_amdgcn_update_dpp(
        0, __float_as_int(x), 0x100 + N /*row_shl:N*/, 0xf, 0xf, false));
    return x + o;
}

// scalar (value,key) max combine — associative+commutative total order
__device__ __forceinline__ void vk_max(float& v, int& k, float ov, int ok) {
    if (ov > v || (ov == v && ok < k)) { v = ov; k = ok; }
}

// ---------------- K1: u = W1a@w2, v = W1b@w2, c0 = b1@w2 + b2 ----------------
__global__ void k1_uvc(const float* __restrict__ W1, const float* __restrict__ b1,
                       const float* __restrict__ w2, const float* __restrict__ b2,
                       char* __restrict__ ws) {
    const int t = threadIdx.x;
    const int r = blockIdx.x;
    if (r == 1025) {   // zero progress counters (ws poisoned 0xAA pre-launch)
        unsigned* bar = (unsigned*)(ws + OFF_BAR);
        for (int i = t; i < 4096; i += 256) bar[i] = 0u;
        return;
    }
    __shared__ float rs[256];
    float acc;
    if (r < 1024) {
        const float* row = W1 + (size_t)r * cD;
        acc = row[t] * w2[t] + row[t + 256] * w2[t + 256];
    } else {
        acc = b1[t] * w2[t] + b1[t + 256] * w2[t + 256];
    }
    rs[t] = acc; __syncthreads();
    for (int o = 128; o; o >>= 1) { if (t < o) rs[t] += rs[t + o]; __syncthreads(); }
    if (t == 0) {
        if (r < 512)        ((float*)(ws + OFF_U))[r] = rs[0];
        else if (r < 1024)  ((float*)(ws + OFF_V))[r - 512] = rs[0];
        else                ((float*)(ws + OFF_SC))[0] = rs[0] + b2[0];   // c0
    }
}

// ---------------- K1b: ua/ub/va/vb = W1{a,b} @ {u,v};  cu = b1·u, cv = b1·v --------
__global__ void k1b_proj(const float* __restrict__ W1, const float* __restrict__ b1,
                         char* __restrict__ ws) {
    __shared__ float ru[256], rv[256];
    const int t = threadIdx.x;
    const int k = blockIdx.x;
    const float* U = (const float*)(ws + OFF_U);
    const float* V = (const float*)(ws + OFF_V);
    const float* row = (k < 1024) ? (W1 + (size_t)k * cD) : b1;
    ru[t] = row[t] * U[t] + row[t + 256] * U[t + 256];
    rv[t] = row[t] * V[t] + row[t + 256] * V[t + 256];
    __syncthreads();
    for (int o = 128; o; o >>= 1) {
        if (t < o) { ru[t] += ru[t + o]; rv[t] += rv[t + o]; }
        __syncthreads();
    }
    if (t == 0) {
        if (k < 512)       { ((float*)(ws + OFF_UA))[k] = ru[0]; ((float*)(ws + OFF_VA))[k] = rv[0]; }
        else if (k < 1024) { ((float*)(ws + OFF_UB))[k - 512] = ru[0]; ((float*)(ws + OFF_VB))[k - 512] = rv[0]; }
        else               { ((float*)(ws + OFF_SC))[1] = ru[0]; ((float*)(ws + OFF_SC))[2] = rv[0]; }
    }
}

// ---------------- K2: gather feats into F copy0, si = f@u, sj = f@v ----------------
__global__ void k2_feat(const int* __restrict__ tok, const float* __restrict__ emb,
                        char* __restrict__ ws) {
    __shared__ float ru[256], rv[256];
    const int t = threadIdx.x;
    const int bs = blockIdx.x;
    const float* U = (const float*)(ws + OFF_U);
    const float* V = (const float*)(ws + OFF_V);
    float* F = (float*)(ws + OFF_F0);
    const int tk = tok[bs];
    const float* src = emb + (size_t)tk * cD;
    float* dst = F + (size_t)bs * cD;
    const float e0 = src[t], e1 = src[t + 256];
    dst[t] = e0; dst[t + 256] = e1;
    ru[t] = e0 * U[t] + e1 * U[t + 256];
    rv[t] = e0 * V[t] + e1 * V[t + 256];
    __syncthreads();
    for (int o = 128; o; o >>= 1) {
        if (t < o) { ru[t] += ru[t + o]; rv[t] += rv[t + o]; }
        __syncthreads();
    }
    if (t == 0) {
        ((float*)(ws + OFF_SI))[bs] = ru[0];
        ((float*)(ws + OFF_SJ))[bs] = rv[0];
    }
}

// ---------------- K3: logits argmax -> cls ----------------
__global__ void k3_cls(const float* __restrict__ posW, const float* __restrict__ posb,
                       char* __restrict__ ws) {
    const int t = threadIdx.x;            // one wave
    const int bs = blockIdx.x;
    const float* frow = (const float*)(ws + OFF_F0) + (size_t)bs * cD;
    float acc = posb[t];
    for (int k = 0; k < cD; k++) acc += frow[k] * posW[(size_t)k * cL + t];
    int idx = t;
    for (int off = 32; off; off >>= 1) {
        float ov = __shfl_down(acc, off, 64);
        int   oi = __shfl_down(idx, off, 64);
        if (ov > acc || (ov == acc && oi < idx)) { acc = ov; idx = oi; }
    }
    if (t == 0) ((int*)(ws + OFF_CLS))[bs] = idx;
}

// ---------------- K4: adjacency bitmask + initial per-row max ----------------
__global__ void k4_adj(char* __restrict__ ws) {
    __shared__ float rsv[256]; __shared__ int rsk[256];
    const int t = threadIdx.x;
    const int bs = blockIdx.x;
    const int b = bs >> 9, r = bs & 511;
    const int* cls = (const int*)(ws + OFF_CLS) + (size_t)b * cS;
    const float* SJ = (const float*)(ws + OFF_SJ) + (size_t)b * cS;
    const float sir = ((const float*)(ws + OFF_SI))[bs];
    const float c0 = ((const float*)(ws + OFF_SC))[0];
    unsigned long long* adjrow = (unsigned long long*)(ws + OFF_ADJ) + (size_t)bs * 8;
    const int cr = cls[r];
    float bv = -INFINITY; int bc = 0;
    for (int p = 0; p < 2; p++) {
        const int c = p * 256 + t;
        int dd = c - r; if (dd < 0) dd = -dd;
        const bool allowed = (c != r) && (dd == 1 || cls[c] == cr);
        unsigned long long m = __ballot(allowed);
        if ((t & 63) == 0) adjrow[p * 4 + (t >> 6)] = m;
        if (allowed) {
            float val = sir + SJ[c] + c0;
            if (val > bv || (val == bv && c < bc)) { bv = val; bc = c; }
        }
    }
    rsv[t] = bv; rsk[t] = bc; __syncthreads();
    for (int o = 128; o; o >>= 1) {
        if (t < o) {
            float s2 = rsv[t + o]; int k2 = rsk[t + o];
            if (s2 > rsv[t] || (s2 == rsv[t] && k2 < rsk[t])) { rsv[t] = s2; rsk[t] = k2; }
        }
        __syncthreads();
    }
    if (t == 0) { ((float*)(ws + OFF_RM))[bs] = rsv[0]; ((int*)(ws + OFF_RA))[bs] = rsk[0]; }
}

// ---------------- K5: parser ----------------------------------------------
// vs round 3 (3316us) / round 2 (2878us):
//  * REVERT the round-3 matvec "unification": h must be branched out so every
//    v_readlane gets a COMPILE-TIME lane immediate. Round 3's runtime lane
//    (2*m+h, h from threadIdx) forced per-readlane v_readfirstlane + addr
//    arithmetic -> +26% total VALU cycles (the measured regression).
//  * KEEP round-3 structure: 4 barriers/iter (wave0 scans rmax directly),
//    wave15 early store/publish, minp poll-skip.
//  * phase-A compare chain 8-deep -> 3-deep tree (assoc+comm comparator,
//    bit-identical result).
//  * s_sleep(1) restored on FAILED poll iterations only.
__global__ void __launch_bounds__(cT, 4)
parse_main(const float* __restrict__ W1, const float* __restrict__ b1,
           char* __restrict__ ws, float* __restrict__ out) {
    const int t  = threadIdx.x;           // 0..1023
    const int b  = blockIdx.x & 15;       // batch (blocks of a batch share an XCD)
    const int g  = blockIdx.x >> 4;       // 0..7
    const int d0 = g * 64;
    const int wf = t >> 6;                // wave id 0..15
    const int ln = t & 63;
    const int wv = wf >> 1;               // k-chunk 0..7
    const int h  = wf & 1;                // half: 0 -> even-pair k, 1 -> odd-pair k

    unsigned long long* F64[2] = {
        (unsigned long long*)(ws + OFF_F0) + (size_t)b * cS * cD / 2,
        (unsigned long long*)(ws + OFF_F1) + (size_t)b * cS * cD / 2 };
    unsigned* prog = (unsigned*)(ws + OFF_BAR) + (size_t)b * 256;   // counters at prog[g*32]
    const float* SCp = (const float*)(ws + OFF_SC);
    const float c0 = SCp[0], cu_c = SCp[1], cv_c = SCp[2];

    // replicated per-block state
    __shared__ unsigned long long AdjL[8 * 512];   // column-major: AdjL[w*512 + r]
    __shared__ float SIl[512], SJl[512], rmax[512];
    __shared__ int   rarg[512];
    __shared__ int   tau[512];                     // last merge step of row r (-1 = never)
    __shared__ unsigned char par[512];             // F-copy parity per row
    __shared__ float rsh[1024];
    __shared__ float ws_si[8], ws_sj[8];
    __shared__ int   s_info;                       // bi | bj<<9 | par_i<<18 | par_j<<19
    __shared__ int   rescanList[516]; __shared__ int nresc;

    // W1 slice: thread (wf,ln) holds 64 k's of chunk wv (h selects pair parity)
    // wreg2[m] = { W1[kbase+4m+2h][d0+ln], W1[kbase+4m+2h+1][d0+ln] }
    const int kbase = wv * 128;
    float2 wreg2[32];
#pragma unroll
    for (int m = 0; m < 32; m++) {
        wreg2[m].x = W1[(size_t)(kbase + 4 * m + 2 * h)     * cD + d0 + ln];
        wreg2[m].y = W1[(size_t)(kbase + 4 * m + 2 * h + 1) * cD + d0 + ln];
    }

    // csi/csj constants (h==0 waves only; they see chunk dims (2ln, 2ln+1))
    const int xk = (wv & 3) * 128 + 2 * ln;
    float cu0 = 0.f, cu1 = 0.f, cv0 = 0.f, cv1 = 0.f;
    if (h == 0) {
        const float* cu_base = (const float*)(ws + ((wv < 4) ? OFF_UA : OFF_UB));
        const float* cvb     = (const float*)(ws + ((wv < 4) ? OFF_VA : OFF_VB));
        cu0 = cu_base[xk]; cu1 = cu_base[xk + 1];
        cv0 = cvb[xk];     cv1 = cvb[xk + 1];
    }

    // replicated init (rows live in t<512)
    if (t < cS) {
        SIl[t]  = ((const float*)(ws + OFF_SI))[b * cS + t];
        SJl[t]  = ((const float*)(ws + OFF_SJ))[b * cS + t];
        rmax[t] = ((const float*)(ws + OFF_RM))[b * cS + t];
        rarg[t] = ((const int*)(ws + OFF_RA))[b * cS + t];
        tau[t]  = -1;
        par[t]  = 0;
        const unsigned long long* AG =
            (const unsigned long long*)(ws + OFF_ADJ) + (size_t)b * cS * 8;
#pragma unroll
        for (int wq = 0; wq < 8; wq++) AdjL[wq * 512 + t] = AG[(size_t)t * 8 + wq];
    }
    float b1v = 0.f;
    if (wf == 15) b1v = b1[d0 + ln];       // storer wave: one output dim per lane
    bool myAlive = true;
    float tot = 0.f;
    int minp = 0;                          // wave0: proven lower bound of prog[*]
    if (t == 0) nresc = 0;
    __syncthreads();   // init barrier (plays B6 for iter 0)

    for (int it = 0; it < cS - 1; ++it) {
        // ---- A: wave0 full argmax over rmax/rarg + dependency poll ----
        if (wf == 0) {
            float v0[8]; int k0[8];
#pragma unroll
            for (int k = 0; k < 8; k++) {
                const int r = k * 64 + ln;
                v0[k] = rmax[r];
                k0[k] = (r << 9) | (rarg[r] & 511);
            }
            // tree combine (assoc+comm comparator -> bit-identical)
            vk_max(v0[0], k0[0], v0[1], k0[1]);
            vk_max(v0[2], k0[2], v0[3], k0[3]);
            vk_max(v0[4], k0[4], v0[5], k0[5]);
            vk_max(v0[6], k0[6], v0[7], k0[7]);
            vk_max(v0[0], k0[0], v0[2], k0[2]);
            vk_max(v0[4], k0[4], v0[6], k0[6]);
            vk_max(v0[0], k0[0], v0[4], k0[4]);
            float bv = v0[0]; int bk = k0[0];
            wave_max64(bv, bk);            // result in lane 63
            const int bk63 = __builtin_amdgcn_readlane(bk, 63);
            const int pbi = bk63 >> 9, pbj = bk63 & 511;
            const int ti = tau[pbi], tj = tau[pbj];       // wave-uniform LDS
            const int pi = (int)par[pbi], pj = (int)par[pbj];
            const int need = (ti > tj ? ti : tj) + 1;
            if (need > minp) {
                const unsigned un = (unsigned)need;
                for (;;) {
                    unsigned v = 0xffffffffu;
                    if (ln < 8) v = __hip_atomic_load(prog + ln * 32, __ATOMIC_RELAXED,
                                                      __HIP_MEMORY_SCOPE_AGENT);
                    if (__ballot(v >= un) == ~0ull) break;
                    __builtin_amdgcn_s_sleep(1);
                }
                minp = need;
            }
            if (ln == 0) {
                s_info = pbi | (pbj << 9) | (pi << 18) | (pj << 19);
                nresc = 0;
                if (g == 0) {
                    const float bfv = __int_as_float(
                        __builtin_amdgcn_readlane(__float_as_int(bv), 63));
                    tot += bfv;
                    out[16 + b * 1022 + it * 2 + 0] = (float)pbi;
                    out[16 + b * 1022 + it * 2 + 1] = (float)pbj;
                }
            }
        }
        __syncthreads();   // B2
        const int info = s_info;
        const int bi = info & 511, bj = (info >> 9) & 511;

        // ---- C: wave-local load + csi/csj + readlane matvec ----
        const int myrow  = (wv < 4) ? bi : bj;
        const int mypar  = (wv < 4) ? ((info >> 18) & 1) : ((info >> 19) & 1);
        unsigned long long xv = __hip_atomic_load(
            F64[mypar] + (size_t)myrow * 256 + (wv & 3) * 64 + ln,
            __ATOMIC_RELAXED, __HIP_MEMORY_SCOPE_AGENT);
        float2 f2; __builtin_memcpy(&f2, &xv, 8);
        // csi/csj partials (h==0 waves; same tree as before -> bit-exact)
        if (h == 0) {
            float csi = f2.x * cu0 + f2.y * cu1;
            float csj = f2.x * cv0 + f2.y * cv1;
            csi += __shfl_down(csi, 32, 64);  csj += __shfl_down(csj, 32, 64);
            csi += __shfl_down(csi, 16, 64);  csj += __shfl_down(csj, 16, 64);
            csi = dpp_shl_add<8>(csi);  csj = dpp_shl_add<8>(csj);
            csi = dpp_shl_add<4>(csi);  csj = dpp_shl_add<4>(csj);
            csi = dpp_shl_add<2>(csi);  csj = dpp_shl_add<2>(csj);
            csi = dpp_shl_add<1>(csi);  csj = dpp_shl_add<1>(csj);
            if (ln == 0) { ws_si[wv] = csi; ws_sj[wv] = csj; }
        }
        // matvec: h branched out -> readlane lane is a compile-time immediate.
        // h=0 -> a0,a1 (x[4m],x[4m+1] = lane 2m); h=1 -> a2,a3 (lane 2m+1)
        {
            const int ix = __float_as_int(f2.x), iy = __float_as_int(f2.y);
            float aP = 0.f, aQ = 0.f;
            if (h == 0) {
#pragma unroll
                for (int m = 0; m < 32; m++) {
                    const float q0 = __int_as_float(__builtin_amdgcn_readlane(ix, 2 * m));
                    const float q1 = __int_as_float(__builtin_amdgcn_readlane(iy, 2 * m));
                    aP = fmaf(wreg2[m].x, q0, aP);
                    aQ = fmaf(wreg2[m].y, q1, aQ);
                }
            } else {
#pragma unroll
                for (int m = 0; m < 32; m++) {
                    const float q0 = __int_as_float(__builtin_amdgcn_readlane(ix, 2 * m + 1));
                    const float q1 = __int_as_float(__builtin_amdgcn_readlane(iy, 2 * m + 1));
                    aP = fmaf(wreg2[m].x, q0, aP);
                    aQ = fmaf(wreg2[m].y, q1, aQ);
                }
            }
            rsh[t] = aP + aQ;   // h=0: a0+a1, h=1: a2+a3
        }
        __syncthreads();   // B3

        if (wf == 15) {
            // ---- S: gather + store + drain + publish (earliest possible) ----
            const int pari = (info >> 18) & 1;
            float p = b1v;
#pragma unroll
            for (int q = 0; q < 8; q++)
                p += rsh[(2 * q) * 64 + ln] + rsh[(2 * q + 1) * 64 + ln];
            // ((b1+P0)+P1)... with P_q = (a0+a1)+(a2+a3): identical tree
            __hip_atomic_store((float*)F64[pari ^ 1] + (size_t)bi * 512 + d0 + ln, p,
                               __ATOMIC_RELAXED, __HIP_MEMORY_SCOPE_AGENT);
            asm volatile("s_waitcnt vmcnt(0)" ::: "memory");
            if (ln == 0)
                __hip_atomic_store(prog + g * 32, (unsigned)(it + 1), __ATOMIC_RELAXED,
                                   __HIP_MEMORY_SCOPE_AGENT);
        } else if (t < cS) {
            // ---- E: replicated sin/sjn (same tree -> bit-exact) ----
            float su = (ln < 8) ? ws_si[ln] : 0.f;
            float sv = (ln < 8) ? ws_sj[ln] : 0.f;
            su = dpp_shl_add<4>(su);  sv = dpp_shl_add<4>(sv);
            su = dpp_shl_add<2>(su);  sv = dpp_shl_add<2>(sv);
            su = dpp_shl_add<1>(su);  sv = dpp_shl_add<1>(sv);
            const float sn = __int_as_float(
                __builtin_amdgcn_readfirstlane(__float_as_int(su))) + cu_c;
            const float jn = __int_as_float(
                __builtin_amdgcn_readfirstlane(__float_as_int(sv))) + cv_c;

            // ---- D: replicated adjacency + incremental rowmax (LDS only) ----
            const float sjn_ = jn;
            const int wbi = bi >> 6, wbj = bj >> 6;
            const unsigned long long mbi = 1ull << (bi & 63), mbj = 1ull << (bj & 63);
            const int r = t;
            if (r == bj) {
                if (myAlive) { myAlive = false; rmax[t] = -INFINITY; }
            } else if (r == bi) {
                // rebuild own row = (row_bi | row_bj) minus {bi,bj}
#pragma unroll
                for (int wq = 0; wq < 8; wq++) {
                    unsigned long long nw = AdjL[wq * 512 + bi] | AdjL[wq * 512 + bj];
                    if (wq == wbi) nw &= ~mbi;
                    if (wq == wbj) nw &= ~mbj;
                    AdjL[wq * 512 + bi] = nw;
                }
                int slot = atomicAdd(&nresc, 1); rescanList[slot] = bi;
                SIl[bi] = sn; SJl[bi] = jn; par[bi] ^= 1; tau[bi] = it;
            } else if (myAlive) {
                unsigned long long wi = AdjL[wbi * 512 + r];
                unsigned long long wj = (wbj == wbi) ? wi : AdjL[wbj * 512 + r];
                const bool nb = ((wi & mbi) | (wj & mbj)) != 0ull;
                if (wbi == wbj) {
                    AdjL[wbi * 512 + r] = (wi & ~(mbi | mbj)) | (nb ? mbi : 0ull);
                } else {
                    AdjL[wbi * 512 + r] = (wi & ~mbi) | (nb ? mbi : 0ull);
                    AdjL[wbj * 512 + r] = wj & ~mbj;
                }
                const int ra = rarg[t];
                if (ra == bi || ra == bj) {
                    int slot = atomicAdd(&nresc, 1); rescanList[slot] = r;
                } else if (nb) {
                    const float val = SIl[r] + sjn_ + c0;
                    if (val > rmax[t] || (val == rmax[t] && bi < ra)) { rmax[t] = val; rarg[t] = bi; }
                }
            }
        }
        __syncthreads();   // B5

        // ---- wave-parallel rescans (DPP reduce, result lane 63) ----
        const int nr = nresc;
        for (int q = wf; q < nr; q += 16) {
            const int r = rescanList[q];
            const float sir = SIl[r];
            float bv2 = -INFINITY; int bc2 = 0x7fffffff;
#pragma unroll
            for (int k = 0; k < 8; k++) {
                const unsigned long long word = AdjL[k * 512 + r];   // wave-uniform
                if ((word >> ln) & 1ull) {
                    const int c = k * 64 + ln;
                    const float val = sir + SJl[c] + c0;
                    if (val > bv2 || (val == bv2 && c < bc2)) { bv2 = val; bc2 = c; }
                }
            }
            wave_max64(bv2, bc2);
            if (ln == 63) { rmax[r] = bv2; rarg[r] = bc2; }
        }
        __syncthreads();   // B6
    }
    if (g == 0 && t == 0) out[b] = tot;
}

extern "C" void kernel_launch(void* const* d_in, const int* in_sizes, int n_in,
                              void* d_out, int out_size, void* d_ws, size_t ws_size,
                              hipStream_t stream) {
    const int*   token_ids = (const int*)d_in[0];
    const float* vocab_emb = (const float*)d_in[1];
    const float* pos_W     = (const float*)d_in[2];
    const float* pos_b     = (const float*)d_in[3];
    const float* W1        = (const float*)d_in[4];
    const float* b1        = (const float*)d_in[5];
    const float* w2        = (const float*)d_in[6];
    const float* b2        = (const float*)d_in[7];
    float* out = (float*)d_out;
    char*  ws  = (char*)d_ws;

    k1_uvc<<<1026, 256, 0, stream>>>(W1, b1, w2, b2, ws);
    k1b_proj<<<1025, 256, 0, stream>>>(W1, b1, ws);
    k2_feat<<<cB * cS, 256, 0, stream>>>(token_ids, vocab_emb, ws);
    k3_cls<<<cB * cS, 64, 0, stream>>>(pos_W, pos_b, ws);
    k4_adj<<<cB * cS, 256, 0, stream>>>(ws);

    // cooperative launch for the co-residency guarantee (custom waits inside)
    void* args[] = { (void*)&W1, (void*)&b1, (void*)&ws, (void*)&out };
    hipLaunchCooperativeKernel((void*)parse_main, dim3(cB * cG), dim3(cT),
                               args, 0, stream);
}

// Round 6
// 2861.105 us; speedup vs baseline: 1.2202x; 1.0296x over previous
//
#include <hip/hip_runtime.h>

#define cB 16
#define cS 512
#define cD 512
#define cL 64
#define cG 8      // blocks per batch
#define cT 1024   // threads per block (16 waves)

// ---------------- workspace layout (bytes) ----------------
constexpr size_t FCOPY   = (size_t)cB * cS * cD * 4;            // 16 MB per F copy
constexpr size_t OFF_F0  = 0;
constexpr size_t OFF_F1  = FCOPY;
constexpr size_t OFF_U   = 2 * FCOPY;                           // D f32
constexpr size_t OFF_V   = OFF_U  + 2048;
constexpr size_t OFF_UA  = OFF_V  + 2048;                       // W1a @ u
constexpr size_t OFF_UB  = OFF_UA + 2048;                       // W1b @ u
constexpr size_t OFF_VA  = OFF_UB + 2048;                       // W1a @ v
constexpr size_t OFF_VB  = OFF_VA + 2048;                       // W1b @ v
constexpr size_t OFF_SC  = OFF_VB + 2048;                       // [c0, cu, cv]
constexpr size_t OFF_SI  = OFF_SC + 64;                         // B*S f32
constexpr size_t OFF_SJ  = OFF_SI + (size_t)cB*cS*4;
constexpr size_t OFF_CLS = OFF_SJ + (size_t)cB*cS*4;
constexpr size_t OFF_ADJ = OFF_CLS+ (size_t)cB*cS*4;            // B*S*8 u64 (row-major)
constexpr size_t OFF_RM  = OFF_ADJ+ (size_t)cB*cS*64;
constexpr size_t OFF_RA  = OFF_RM + (size_t)cB*cS*4;
// prog: per batch 8 counters at 128B stride (no false sharing). 16 KB total.
constexpr size_t OFF_BAR = ((OFF_RA + (size_t)cB*cS*4 + 127) & ~(size_t)127);

// ---------------- DPP max+key reduction helpers (order-independent) ----------
template <int CTRL, int RMASK>
__device__ __forceinline__ void dpp_max_step(float& v, int& k) {
    const float ov = __int_as_float(__builtin_amdgcn_update_dpp(
        (int)0xff800000u, __float_as_int(v), CTRL, RMASK, 0xf, false));
    const int ok = __builtin_amdgcn_update_dpp(
        0x7fffffff, k, CTRL, RMASK, 0xf, false);
    if (ov > v || (ov == v && ok < k)) { v = ov; k = ok; }
}

// full 64-lane (value,key) max; result lands in lane 63
__device__ __forceinline__ void wave_max64(float& v, int& k) {
    dpp_max_step<0x111, 0xf>(v, k);   // row_shr:1
    dpp_max_step<0x112, 0xf>(v, k);   // row_shr:2
    dpp_max_step<0x114, 0xf>(v, k);   // row_shr:4
    dpp_max_step<0x118, 0xf>(v, k);   // row_shr:8
    dpp_max_step<0x142, 0xa>(v, k);   // row_bcast:15 rows 1,3
    dpp_max_step<0x143, 0xc>(v, k);   // row_bcast:31 rows 2,3
}

// x + (lane i+N value); bit-exact replacement of __shfl_down(x,N) for N<=8
// in a down-sweep tree (only prefix lanes feed later steps).
template <int N>
__device__ __forceinline__ float dpp_shl_add(float x) {
    const float o = __int_as_float(__builtin_amdgcn_update_dpp(
        0, __float_as_int(x), 0x100 + N /*row_shl:N*/, 0xf, 0xf, false));
    return x + o;
}

// scalar (value,key) max combine — associative+commutative total order
__device__ __forceinline__ void vk_max(float& v, int& k, float ov, int ok) {
    if (ov > v || (ov == v && ok < k)) { v = ov; k = ok; }
}

// ---------------- K1: u = W1a@w2, v = W1b@w2, c0 = b1@w2 + b2 ----------------
__global__ void k1_uvc(const float* __restrict__ W1, const float* __restrict__ b1,
                       const float* __restrict__ w2, const float* __restrict__ b2,
                       char* __restrict__ ws) {
    const int t = threadIdx.x;
    const int r = blockIdx.x;
    if (r == 1025) {   // zero progress counters (ws poisoned 0xAA pre-launch)
        unsigned* bar = (unsigned*)(ws + OFF_BAR);
        for (int i = t; i < 4096; i += 256) bar[i] = 0u;
        return;
    }
    __shared__ float rs[256];
    float acc;
    if (r < 1024) {
        const float* row = W1 + (size_t)r * cD;
        acc = row[t] * w2[t] + row[t + 256] * w2[t + 256];
    } else {
        acc = b1[t] * w2[t] + b1[t + 256] * w2[t + 256];
    }
    rs[t] = acc; __syncthreads();
    for (int o = 128; o; o >>= 1) { if (t < o) rs[t] += rs[t + o]; __syncthreads(); }
    if (t == 0) {
        if (r < 512)        ((float*)(ws + OFF_U))[r] = rs[0];
        else if (r < 1024)  ((float*)(ws + OFF_V))[r - 512] = rs[0];
        else                ((float*)(ws + OFF_SC))[0] = rs[0] + b2[0];   // c0
    }
}

// ---------------- K1b: ua/ub/va/vb = W1{a,b} @ {u,v};  cu = b1·u, cv = b1·v --------
__global__ void k1b_proj(const float* __restrict__ W1, const float* __restrict__ b1,
                         char* __restrict__ ws) {
    __shared__ float ru[256], rv[256];
    const int t = threadIdx.x;
    const int k = blockIdx.x;
    const float* U = (const float*)(ws + OFF_U);
    const float* V = (const float*)(ws + OFF_V);
    const float* row = (k < 1024) ? (W1 + (size_t)k * cD) : b1;
    ru[t] = row[t] * U[t] + row[t + 256] * U[t + 256];
    rv[t] = row[t] * V[t] + row[t + 256] * V[t + 256];
    __syncthreads();
    for (int o = 128; o; o >>= 1) {
        if (t < o) { ru[t] += ru[t + o]; rv[t] += rv[t + o]; }
        __syncthreads();
    }
    if (t == 0) {
        if (k < 512)       { ((float*)(ws + OFF_UA))[k] = ru[0]; ((float*)(ws + OFF_VA))[k] = rv[0]; }
        else if (k < 1024) { ((float*)(ws + OFF_UB))[k - 512] = ru[0]; ((float*)(ws + OFF_VB))[k - 512] = rv[0]; }
        else               { ((float*)(ws + OFF_SC))[1] = ru[0]; ((float*)(ws + OFF_SC))[2] = rv[0]; }
    }
}

// ---------------- K2: gather feats into F copy0, si = f@u, sj = f@v ----------------
__global__ void k2_feat(const int* __restrict__ tok, const float* __restrict__ emb,
                        char* __restrict__ ws) {
    __shared__ float ru[256], rv[256];
    const int t = threadIdx.x;
    const int bs = blockIdx.x;
    const float* U = (const float*)(ws + OFF_U);
    const float* V = (const float*)(ws + OFF_V);
    float* F = (float*)(ws + OFF_F0);
    const int tk = tok[bs];
    const float* src = emb + (size_t)tk * cD;
    float* dst = F + (size_t)bs * cD;
    const float e0 = src[t], e1 = src[t + 256];
    dst[t] = e0; dst[t + 256] = e1;
    ru[t] = e0 * U[t] + e1 * U[t + 256];
    rv[t] = e0 * V[t] + e1 * V[t + 256];
    __syncthreads();
    for (int o = 128; o; o >>= 1) {
        if (t < o) { ru[t] += ru[t + o]; rv[t] += rv[t + o]; }
        __syncthreads();
    }
    if (t == 0) {
        ((float*)(ws + OFF_SI))[bs] = ru[0];
        ((float*)(ws + OFF_SJ))[bs] = rv[0];
    }
}

// ---------------- K3: logits argmax -> cls ----------------
__global__ void k3_cls(const float* __restrict__ posW, const float* __restrict__ posb,
                       char* __restrict__ ws) {
    const int t = threadIdx.x;            // one wave
    const int bs = blockIdx.x;
    const float* frow = (const float*)(ws + OFF_F0) + (size_t)bs * cD;
    float acc = posb[t];
    for (int k = 0; k < cD; k++) acc += frow[k] * posW[(size_t)k * cL + t];
    int idx = t;
    for (int off = 32; off; off >>= 1) {
        float ov = __shfl_down(acc, off, 64);
        int   oi = __shfl_down(idx, off, 64);
        if (ov > acc || (ov == acc && oi < idx)) { acc = ov; idx = oi; }
    }
    if (t == 0) ((int*)(ws + OFF_CLS))[bs] = idx;
}

// ---------------- K4: adjacency bitmask + initial per-row max ----------------
__global__ void k4_adj(char* __restrict__ ws) {
    __shared__ float rsv[256]; __shared__ int rsk[256];
    const int t = threadIdx.x;
    const int bs = blockIdx.x;
    const int b = bs >> 9, r = bs & 511;
    const int* cls = (const int*)(ws + OFF_CLS) + (size_t)b * cS;
    const float* SJ = (const float*)(ws + OFF_SJ) + (size_t)b * cS;
    const float sir = ((const float*)(ws + OFF_SI))[bs];
    const float c0 = ((const float*)(ws + OFF_SC))[0];
    unsigned long long* adjrow = (unsigned long long*)(ws + OFF_ADJ) + (size_t)bs * 8;
    const int cr = cls[r];
    float bv = -INFINITY; int bc = 0;
    for (int p = 0; p < 2; p++) {
        const int c = p * 256 + t;
        int dd = c - r; if (dd < 0) dd = -dd;
        const bool allowed = (c != r) && (dd == 1 || cls[c] == cr);
        unsigned long long m = __ballot(allowed);
        if ((t & 63) == 0) adjrow[p * 4 + (t >> 6)] = m;
        if (allowed) {
            float val = sir + SJ[c] + c0;
            if (val > bv || (val == bv && c < bc)) { bv = val; bc = c; }
        }
    }
    rsv[t] = bv; rsk[t] = bc; __syncthreads();
    for (int o = 128; o; o >>= 1) {
        if (t < o) {
            float s2 = rsv[t + o]; int k2 = rsk[t + o];
            if (s2 > rsv[t] || (s2 == rsv[t] && k2 < rsk[t])) { rsv[t] = s2; rsk[t] = k2; }
        }
        __syncthreads();
    }
    if (t == 0) { ((float*)(ws + OFF_RM))[bs] = rsv[0]; ((int*)(ws + OFF_RA))[bs] = rsk[0]; }
}

// ---------------- K5: parser ----------------------------------------------
// Round-4 skeleton (verified 2774us: 3 barriers + rescan + B6) + safe deltas:
//  * dependency poll moved OUT of wave0's serial head into phase C, per-wave:
//    each wave polls only for its own row (need = tau[myrow]+1 vs private
//    minp). A phase = pure argmax -> s_info -> B2. Deadlock-safe: prog is
//    published unconditionally by every block every iteration (as round 4).
//  * tau+par packed into tp[512]: one uniform LDS read per wave in C.
//  * out[] stores removed from the loop: bi/bj logged to LDS iterLog,
//    written back once after the loop (wave0's C load no longer waits on
//    out-store vmcnt acks).
// Round-5's barrier-free rescan tail (suspected deadlock) is NOT included.
__global__ void __launch_bounds__(cT, 4)
parse_main(const float* __restrict__ W1, const float* __restrict__ b1,
           char* __restrict__ ws, float* __restrict__ out) {
    const int t  = threadIdx.x;           // 0..1023
    const int b  = blockIdx.x & 15;       // batch (blocks of a batch share an XCD)
    const int g  = blockIdx.x >> 4;       // 0..7
    const int d0 = g * 64;
    const int wf = t >> 6;                // wave id 0..15
    const int ln = t & 63;
    const int wv = wf >> 1;               // k-chunk 0..7
    const int h  = wf & 1;                // half: 0 -> even-pair k, 1 -> odd-pair k

    unsigned long long* F64[2] = {
        (unsigned long long*)(ws + OFF_F0) + (size_t)b * cS * cD / 2,
        (unsigned long long*)(ws + OFF_F1) + (size_t)b * cS * cD / 2 };
    unsigned* prog = (unsigned*)(ws + OFF_BAR) + (size_t)b * 256;   // counters at prog[g*32]
    const float* SCp = (const float*)(ws + OFF_SC);
    const float c0 = SCp[0], cu_c = SCp[1], cv_c = SCp[2];

    // replicated per-block state
    __shared__ unsigned long long AdjL[8 * 512];   // column-major: AdjL[w*512 + r]
    __shared__ float SIl[512], SJl[512], rmax[512];
    __shared__ int   rarg[512];
    __shared__ int   tp[512];                      // (tau<<1) | par
    __shared__ float rsh[1024];
    __shared__ float ws_si[8], ws_sj[8];
    __shared__ int   s_info;                       // bi | bj<<9
    __shared__ int   rescanList[516]; __shared__ int nresc;
    __shared__ int   iterLog[512];                 // bi|bj<<9 per iteration

    // W1 slice: thread (wf,ln) holds 64 k's of chunk wv (h selects pair parity)
    const int kbase = wv * 128;
    float2 wreg2[32];
#pragma unroll
    for (int m = 0; m < 32; m++) {
        wreg2[m].x = W1[(size_t)(kbase + 4 * m + 2 * h)     * cD + d0 + ln];
        wreg2[m].y = W1[(size_t)(kbase + 4 * m + 2 * h + 1) * cD + d0 + ln];
    }

    // csi/csj constants (h==0 waves only; they see chunk dims (2ln, 2ln+1))
    const int xk = (wv & 3) * 128 + 2 * ln;
    float cu0 = 0.f, cu1 = 0.f, cv0 = 0.f, cv1 = 0.f;
    if (h == 0) {
        const float* cu_base = (const float*)(ws + ((wv < 4) ? OFF_UA : OFF_UB));
        const float* cvb     = (const float*)(ws + ((wv < 4) ? OFF_VA : OFF_VB));
        cu0 = cu_base[xk]; cu1 = cu_base[xk + 1];
        cv0 = cvb[xk];     cv1 = cvb[xk + 1];
    }

    // replicated init (rows live in t<512)
    if (t < cS) {
        SIl[t]  = ((const float*)(ws + OFF_SI))[b * cS + t];
        SJl[t]  = ((const float*)(ws + OFF_SJ))[b * cS + t];
        rmax[t] = ((const float*)(ws + OFF_RM))[b * cS + t];
        rarg[t] = ((const int*)(ws + OFF_RA))[b * cS + t];
        tp[t]   = -2;                    // tau=-1, par=0
        const unsigned long long* AG =
            (const unsigned long long*)(ws + OFF_ADJ) + (size_t)b * cS * 8;
#pragma unroll
        for (int wq = 0; wq < 8; wq++) AdjL[wq * 512 + t] = AG[(size_t)t * 8 + wq];
    }
    float b1v = 0.f;
    if (wf == 15) b1v = b1[d0 + ln];       // storer wave: one output dim per lane
    bool myAlive = true;
    float tot = 0.f;
    int minp = 0;                          // per-thread proven lower bound of prog[*]
    if (t == 0) nresc = 0;
    __syncthreads();   // init barrier

    for (int it = 0; it < cS - 1; ++it) {
        // ---- A: wave0 pure argmax over rmax/rarg (no poll, no tau reads) ----
        if (wf == 0) {
            float v0[8]; int k0[8];
#pragma unroll
            for (int k = 0; k < 8; k++) {
                const int r = k * 64 + ln;
                v0[k] = rmax[r];
                k0[k] = (r << 9) | (rarg[r] & 511);
            }
            vk_max(v0[0], k0[0], v0[1], k0[1]);
            vk_max(v0[2], k0[2], v0[3], k0[3]);
            vk_max(v0[4], k0[4], v0[5], k0[5]);
            vk_max(v0[6], k0[6], v0[7], k0[7]);
            vk_max(v0[0], k0[0], v0[2], k0[2]);
            vk_max(v0[4], k0[4], v0[6], k0[6]);
            vk_max(v0[0], k0[0], v0[4], k0[4]);
            float bv = v0[0]; int bk = k0[0];
            wave_max64(bv, bk);            // result in lane 63
            const int bk63 = __builtin_amdgcn_readlane(bk, 63);
            const int pbi = bk63 >> 9, pbj = bk63 & 511;
            if (ln == 0) {
                const int info0 = pbi | (pbj << 9);
                s_info = info0;
                iterLog[it] = info0;
                nresc = 0;
                if (g == 0) {
                    tot += __int_as_float(
                        __builtin_amdgcn_readlane(__float_as_int(bv), 63));
                }
            }
        }
        __syncthreads();   // B2
        const int info = s_info;
        const int bi = info & 511, bj = (info >> 9) & 511;

        // ---- C: per-wave freshness poll + load + csi/csj + readlane matvec ----
        const int myrow = (wv < 4) ? bi : bj;
        const int tpr   = tp[myrow];               // wave-uniform LDS read
        const int mypar = tpr & 1;
        const int need  = (tpr >> 1) + 1;          // tau=-1 -> need=0 (skip)
        int pari = 0;
        if (wf == 15) pari = tp[bi] & 1;           // store-target parity (old)
        if (need > minp) {
            const unsigned un = (unsigned)need;
            for (;;) {
                unsigned v = 0xffffffffu;
                if (ln < 8) v = __hip_atomic_load(prog + ln * 32, __ATOMIC_RELAXED,
                                                  __HIP_MEMORY_SCOPE_AGENT);
                if (__ballot(v >= un) == ~0ull) break;
                __builtin_amdgcn_s_sleep(1);
            }
            minp = need;
        }
        unsigned long long xv = __hip_atomic_load(
            F64[mypar] + (size_t)myrow * 256 + (wv & 3) * 64 + ln,
            __ATOMIC_RELAXED, __HIP_MEMORY_SCOPE_AGENT);
        float2 f2; __builtin_memcpy(&f2, &xv, 8);
        // csi/csj partials (h==0 waves; same tree -> bit-exact)
        if (h == 0) {
            float csi = f2.x * cu0 + f2.y * cu1;
            float csj = f2.x * cv0 + f2.y * cv1;
            csi += __shfl_down(csi, 32, 64);  csj += __shfl_down(csj, 32, 64);
            csi += __shfl_down(csi, 16, 64);  csj += __shfl_down(csj, 16, 64);
            csi = dpp_shl_add<8>(csi);  csj = dpp_shl_add<8>(csj);
            csi = dpp_shl_add<4>(csi);  csj = dpp_shl_add<4>(csj);
            csi = dpp_shl_add<2>(csi);  csj = dpp_shl_add<2>(csj);
            csi = dpp_shl_add<1>(csi);  csj = dpp_shl_add<1>(csj);
            if (ln == 0) { ws_si[wv] = csi; ws_sj[wv] = csj; }
        }
        // matvec: h branched out -> readlane lane is a compile-time immediate.
        {
            const int ix = __float_as_int(f2.x), iy = __float_as_int(f2.y);
            float aP = 0.f, aQ = 0.f;
            if (h == 0) {
#pragma unroll
                for (int m = 0; m < 32; m++) {
                    const float q0 = __int_as_float(__builtin_amdgcn_readlane(ix, 2 * m));
                    const float q1 = __int_as_float(__builtin_amdgcn_readlane(iy, 2 * m));
                    aP = fmaf(wreg2[m].x, q0, aP);
                    aQ = fmaf(wreg2[m].y, q1, aQ);
                }
            } else {
#pragma unroll
                for (int m = 0; m < 32; m++) {
                    const float q0 = __int_as_float(__builtin_amdgcn_readlane(ix, 2 * m + 1));
                    const float q1 = __int_as_float(__builtin_amdgcn_readlane(iy, 2 * m + 1));
                    aP = fmaf(wreg2[m].x, q0, aP);
                    aQ = fmaf(wreg2[m].y, q1, aQ);
                }
            }
            rsh[t] = aP + aQ;   // h=0: a0+a1, h=1: a2+a3
        }
        __syncthreads();   // B3

        if (wf == 15) {
            // ---- S: gather + store + drain + publish (earliest possible) ----
            float p = b1v;
#pragma unroll
            for (int q = 0; q < 8; q++)
                p += rsh[(2 * q) * 64 + ln] + rsh[(2 * q + 1) * 64 + ln];
            // ((b1+P0)+P1)... with P_q = (a0+a1)+(a2+a3): identical tree
            __hip_atomic_store((float*)F64[pari ^ 1] + (size_t)bi * 512 + d0 + ln, p,
                               __ATOMIC_RELAXED, __HIP_MEMORY_SCOPE_AGENT);
            asm volatile("s_waitcnt vmcnt(0)" ::: "memory");
            if (ln == 0)
                __hip_atomic_store(prog + g * 32, (unsigned)(it + 1), __ATOMIC_RELAXED,
                                   __HIP_MEMORY_SCOPE_AGENT);
        } else if (t < cS) {
            // ---- E: replicated sin/sjn (same tree -> bit-exact) ----
            float su = (ln < 8) ? ws_si[ln] : 0.f;
            float sv = (ln < 8) ? ws_sj[ln] : 0.f;
            su = dpp_shl_add<4>(su);  sv = dpp_shl_add<4>(sv);
            su = dpp_shl_add<2>(su);  sv = dpp_shl_add<2>(sv);
            su = dpp_shl_add<1>(su);  sv = dpp_shl_add<1>(sv);
            const float sn = __int_as_float(
                __builtin_amdgcn_readfirstlane(__float_as_int(su))) + cu_c;
            const float jn = __int_as_float(
                __builtin_amdgcn_readfirstlane(__float_as_int(sv))) + cv_c;

            // ---- D: replicated adjacency + incremental rowmax (LDS only) ----
            const float sjn_ = jn;
            const int wbi = bi >> 6, wbj = bj >> 6;
            const unsigned long long mbi = 1ull << (bi & 63), mbj = 1ull << (bj & 63);
            const int r = t;
            if (r == bj) {
                if (myAlive) { myAlive = false; rmax[t] = -INFINITY; }
            } else if (r == bi) {
                // rebuild own row = (row_bi | row_bj) minus {bi,bj}
#pragma unroll
                for (int wq = 0; wq < 8; wq++) {
                    unsigned long long nw = AdjL[wq * 512 + bi] | AdjL[wq * 512 + bj];
                    if (wq == wbi) nw &= ~mbi;
                    if (wq == wbj) nw &= ~mbj;
                    AdjL[wq * 512 + bi] = nw;
                }
                int slot = atomicAdd(&nresc, 1); rescanList[slot] = bi;
                SIl[bi] = sn; SJl[bi] = jn;
                tp[bi] = (it << 1) | ((tp[bi] & 1) ^ 1);
            } else if (myAlive) {
                unsigned long long wi = AdjL[wbi * 512 + r];
                unsigned long long wj = (wbj == wbi) ? wi : AdjL[wbj * 512 + r];
                const bool nb = ((wi & mbi) | (wj & mbj)) != 0ull;
                if (wbi == wbj) {
                    AdjL[wbi * 512 + r] = (wi & ~(mbi | mbj)) | (nb ? mbi : 0ull);
                } else {
                    AdjL[wbi * 512 + r] = (wi & ~mbi) | (nb ? mbi : 0ull);
                    AdjL[wbj * 512 + r] = wj & ~mbj;
                }
                const int ra = rarg[t];
                if (ra == bi || ra == bj) {
                    int slot = atomicAdd(&nresc, 1); rescanList[slot] = r;
                } else if (nb) {
                    const float val = SIl[r] + sjn_ + c0;
                    if (val > rmax[t] || (val == rmax[t] && bi < ra)) { rmax[t] = val; rarg[t] = bi; }
                }
            }
        }
        __syncthreads();   // B5

        // ---- wave-parallel rescans (DPP reduce, result lane 63) ----
        const int nr = nresc;
        for (int q = wf; q < nr; q += 16) {
            const int r = rescanList[q];
            const float sir = SIl[r];
            float bv2 = -INFINITY; int bc2 = 0x7fffffff;
#pragma unroll
            for (int k = 0; k < 8; k++) {
                const unsigned long long word = AdjL[k * 512 + r];   // wave-uniform
                if ((word >> ln) & 1ull) {
                    const int c = k * 64 + ln;
                    const float val = sir + SJl[c] + c0;
                    if (val > bv2 || (val == bv2 && c < bc2)) { bv2 = val; bc2 = c; }
                }
            }
            wave_max64(bv2, bc2);
            if (ln == 63) { rmax[r] = bv2; rarg[r] = bc2; }
        }
        __syncthreads();   // B6
    }

    // ---- final writeback: parse tree from iterLog + total score ----
    __syncthreads();
    if (g == 0) {
        if (t < 2 * (cS - 1)) {
            const int e = iterLog[t >> 1];
            const int val = (t & 1) ? ((e >> 9) & 511) : (e & 511);
            out[16 + b * 1022 + t] = (float)val;
        }
        if (t == 0) out[b] = tot;
    }
}

extern "C" void kernel_launch(void* const* d_in, const int* in_sizes, int n_in,
                              void* d_out, int out_size, void* d_ws, size_t ws_size,
                              hipStream_t stream) {
    const int*   token_ids = (const int*)d_in[0];
    const float* vocab_emb = (const float*)d_in[1];
    const float* pos_W     = (const float*)d_in[2];
    const float* pos_b     = (const float*)d_in[3];
    const float* W1        = (const float*)d_in[4];
    const float* b1        = (const float*)d_in[5];
    const float* w2        = (const float*)d_in[6];
    const float* b2        = (const float*)d_in[7];
    float* out = (float*)d_out;
    char*  ws  = (char*)d_ws;

    k1_uvc<<<1026, 256, 0, stream>>>(W1, b1, w2, b2, ws);
    k1b_proj<<<1025, 256, 0, stream>>>(W1, b1, ws);
    k2_feat<<<cB * cS, 256, 0, stream>>>(token_ids, vocab_emb, ws);
    k3_cls<<<cB * cS, 64, 0, stream>>>(pos_W, pos_b, ws);
    k4_adj<<<cB * cS, 256, 0, stream>>>(ws);

    // cooperative launch for the co-residency guarantee (custom waits inside)
    void* args[] = { (void*)&W1, (void*)&b1, (void*)&ws, (void*)&out };
    hipLaunchCooperativeKernel((void*)parse_main, dim3(cB * cG), dim3(cT),
                               args, 0, stream);
}

// Round 7
// 2690.059 us; speedup vs baseline: 1.2978x; 1.0636x over previous
//
#include <hip/hip_runtime.h>

#define cB 16
#define cS 512
#define cD 512
#define cL 64
#define cG 8      // blocks per batch
#define cT 1024   // threads per block (16 waves)

// ---------------- workspace layout (bytes) ----------------
constexpr size_t FCOPY   = (size_t)cB * cS * cD * 4;            // 16 MB per F copy
constexpr size_t OFF_F0  = 0;
constexpr size_t OFF_F1  = FCOPY;
constexpr size_t OFF_U   = 2 * FCOPY;                           // D f32
constexpr size_t OFF_V   = OFF_U  + 2048;
constexpr size_t OFF_UA  = OFF_V  + 2048;                       // W1a @ u
constexpr size_t OFF_UB  = OFF_UA + 2048;                       // W1b @ u
constexpr size_t OFF_VA  = OFF_UB + 2048;                       // W1a @ v
constexpr size_t OFF_VB  = OFF_VA + 2048;                       // W1b @ v
constexpr size_t OFF_SC  = OFF_VB + 2048;                       // [c0, cu, cv]
constexpr size_t OFF_SI  = OFF_SC + 64;                         // B*S f32
constexpr size_t OFF_SJ  = OFF_SI + (size_t)cB*cS*4;
constexpr size_t OFF_CLS = OFF_SJ + (size_t)cB*cS*4;
constexpr size_t OFF_ADJ = OFF_CLS+ (size_t)cB*cS*4;            // B*S*8 u64 (row-major)
constexpr size_t OFF_RM  = OFF_ADJ+ (size_t)cB*cS*64;
constexpr size_t OFF_RA  = OFF_RM + (size_t)cB*cS*4;
// prog: per batch 8 counters at 128B stride (no false sharing). 16 KB total.
constexpr size_t OFF_BAR = ((OFF_RA + (size_t)cB*cS*4 + 127) & ~(size_t)127);

// ---------------- DPP max+key reduction helpers (order-independent) ----------
template <int CTRL, int RMASK>
__device__ __forceinline__ void dpp_max_step(float& v, int& k) {
    const float ov = __int_as_float(__builtin_amdgcn_update_dpp(
        (int)0xff800000u, __float_as_int(v), CTRL, RMASK, 0xf, false));
    const int ok = __builtin_amdgcn_update_dpp(
        0x7fffffff, k, CTRL, RMASK, 0xf, false);
    if (ov > v || (ov == v && ok < k)) { v = ov; k = ok; }
}

// full 64-lane (value,key) max; result lands in lane 63
__device__ __forceinline__ void wave_max64(float& v, int& k) {
    dpp_max_step<0x111, 0xf>(v, k);   // row_shr:1
    dpp_max_step<0x112, 0xf>(v, k);   // row_shr:2
    dpp_max_step<0x114, 0xf>(v, k);   // row_shr:4
    dpp_max_step<0x118, 0xf>(v, k);   // row_shr:8
    dpp_max_step<0x142, 0xa>(v, k);   // row_bcast:15 rows 1,3
    dpp_max_step<0x143, 0xc>(v, k);   // row_bcast:31 rows 2,3
}

// x + (lane i+N value); bit-exact replacement of __shfl_down(x,N) for N<=8
// in a down-sweep tree (only prefix lanes feed later steps).
template <int N>
__device__ __forceinline__ float dpp_shl_add(float x) {
    const float o = __int_as_float(__builtin_amdgcn_update_dpp(
        0, __float_as_int(x), 0x100 + N /*row_shl:N*/, 0xf, 0xf, false));
    return x + o;
}

// scalar (value,key) max combine — associative+commutative total order
__device__ __forceinline__ void vk_max(float& v, int& k, float ov, int ok) {
    if (ov > v || (ov == v && ok < k)) { v = ov; k = ok; }
}

// ---------------- K1: u = W1a@w2, v = W1b@w2, c0 = b1@w2 + b2 ----------------
__global__ void k1_uvc(const float* __restrict__ W1, const float* __restrict__ b1,
                       const float* __restrict__ w2, const float* __restrict__ b2,
                       char* __restrict__ ws) {
    const int t = threadIdx.x;
    const int r = blockIdx.x;
    if (r == 1025) {   // zero progress counters (ws poisoned 0xAA pre-launch)
        unsigned* bar = (unsigned*)(ws + OFF_BAR);
        for (int i = t; i < 4096; i += 256) bar[i] = 0u;
        return;
    }
    __shared__ float rs[256];
    float acc;
    if (r < 1024) {
        const float* row = W1 + (size_t)r * cD;
        acc = row[t] * w2[t] + row[t + 256] * w2[t + 256];
    } else {
        acc = b1[t] * w2[t] + b1[t + 256] * w2[t + 256];
    }
    rs[t] = acc; __syncthreads();
    for (int o = 128; o; o >>= 1) { if (t < o) rs[t] += rs[t + o]; __syncthreads(); }
    if (t == 0) {
        if (r < 512)        ((float*)(ws + OFF_U))[r] = rs[0];
        else if (r < 1024)  ((float*)(ws + OFF_V))[r - 512] = rs[0];
        else                ((float*)(ws + OFF_SC))[0] = rs[0] + b2[0];   // c0
    }
}

// ---------------- K1b: ua/ub/va/vb = W1{a,b} @ {u,v};  cu = b1·u, cv = b1·v --------
__global__ void k1b_proj(const float* __restrict__ W1, const float* __restrict__ b1,
                         char* __restrict__ ws) {
    __shared__ float ru[256], rv[256];
    const int t = threadIdx.x;
    const int k = blockIdx.x;
    const float* U = (const float*)(ws + OFF_U);
    const float* V = (const float*)(ws + OFF_V);
    const float* row = (k < 1024) ? (W1 + (size_t)k * cD) : b1;
    ru[t] = row[t] * U[t] + row[t + 256] * U[t + 256];
    rv[t] = row[t] * V[t] + row[t + 256] * V[t + 256];
    __syncthreads();
    for (int o = 128; o; o >>= 1) {
        if (t < o) { ru[t] += ru[t + o]; rv[t] += rv[t + o]; }
        __syncthreads();
    }
    if (t == 0) {
        if (k < 512)       { ((float*)(ws + OFF_UA))[k] = ru[0]; ((float*)(ws + OFF_VA))[k] = rv[0]; }
        else if (k < 1024) { ((float*)(ws + OFF_UB))[k - 512] = ru[0]; ((float*)(ws + OFF_VB))[k - 512] = rv[0]; }
        else               { ((float*)(ws + OFF_SC))[1] = ru[0]; ((float*)(ws + OFF_SC))[2] = rv[0]; }
    }
}

// ---------------- K2: gather feats into F copy0, si = f@u, sj = f@v ----------------
__global__ void k2_feat(const int* __restrict__ tok, const float* __restrict__ emb,
                        char* __restrict__ ws) {
    __shared__ float ru[256], rv[256];
    const int t = threadIdx.x;
    const int bs = blockIdx.x;
    const float* U = (const float*)(ws + OFF_U);
    const float* V = (const float*)(ws + OFF_V);
    float* F = (float*)(ws + OFF_F0);
    const int tk = tok[bs];
    const float* src = emb + (size_t)tk * cD;
    float* dst = F + (size_t)bs * cD;
    const float e0 = src[t], e1 = src[t + 256];
    dst[t] = e0; dst[t + 256] = e1;
    ru[t] = e0 * U[t] + e1 * U[t + 256];
    rv[t] = e0 * V[t] + e1 * V[t + 256];
    __syncthreads();
    for (int o = 128; o; o >>= 1) {
        if (t < o) { ru[t] += ru[t + o]; rv[t] += rv[t + o]; }
        __syncthreads();
    }
    if (t == 0) {
        ((float*)(ws + OFF_SI))[bs] = ru[0];
        ((float*)(ws + OFF_SJ))[bs] = rv[0];
    }
}

// ---------------- K3: logits argmax -> cls ----------------
__global__ void k3_cls(const float* __restrict__ posW, const float* __restrict__ posb,
                       char* __restrict__ ws) {
    const int t = threadIdx.x;            // one wave
    const int bs = blockIdx.x;
    const float* frow = (const float*)(ws + OFF_F0) + (size_t)bs * cD;
    float acc = posb[t];
    for (int k = 0; k < cD; k++) acc += frow[k] * posW[(size_t)k * cL + t];
    int idx = t;
    for (int off = 32; off; off >>= 1) {
        float ov = __shfl_down(acc, off, 64);
        int   oi = __shfl_down(idx, off, 64);
        if (ov > acc || (ov == acc && oi < idx)) { acc = ov; idx = oi; }
    }
    if (t == 0) ((int*)(ws + OFF_CLS))[bs] = idx;
}

// ---------------- K4: adjacency bitmask + initial per-row max ----------------
__global__ void k4_adj(char* __restrict__ ws) {
    __shared__ float rsv[256]; __shared__ int rsk[256];
    const int t = threadIdx.x;
    const int bs = blockIdx.x;
    const int b = bs >> 9, r = bs & 511;
    const int* cls = (const int*)(ws + OFF_CLS) + (size_t)b * cS;
    const float* SJ = (const float*)(ws + OFF_SJ) + (size_t)b * cS;
    const float sir = ((const float*)(ws + OFF_SI))[bs];
    const float c0 = ((const float*)(ws + OFF_SC))[0];
    unsigned long long* adjrow = (unsigned long long*)(ws + OFF_ADJ) + (size_t)bs * 8;
    const int cr = cls[r];
    float bv = -INFINITY; int bc = 0;
    for (int p = 0; p < 2; p++) {
        const int c = p * 256 + t;
        int dd = c - r; if (dd < 0) dd = -dd;
        const bool allowed = (c != r) && (dd == 1 || cls[c] == cr);
        unsigned long long m = __ballot(allowed);
        if ((t & 63) == 0) adjrow[p * 4 + (t >> 6)] = m;
        if (allowed) {
            float val = sir + SJ[c] + c0;
            if (val > bv || (val == bv && c < bc)) { bv = val; bc = c; }
        }
    }
    rsv[t] = bv; rsk[t] = bc; __syncthreads();
    for (int o = 128; o; o >>= 1) {
        if (t < o) {
            float s2 = rsv[t + o]; int k2 = rsk[t + o];
            if (s2 > rsv[t] || (s2 == rsv[t] && k2 < rsk[t])) { rsv[t] = s2; rsk[t] = k2; }
        }
        __syncthreads();
    }
    if (t == 0) { ((float*)(ws + OFF_RM))[bs] = rsv[0]; ((int*)(ws + OFF_RA))[bs] = rsk[0]; }
}

// ---------------- K5: parser ----------------------------------------------
// vs round 6 (2699us):
//  * NARROWED POLL: wave reading u64 quarter (wv&3) depends only on producer
//    blocks 2*(wv&3) and 2*(wv&3)+1 -> poll those 2 counters, not all 8.
//    Waves with fast producers start load+matvec early (C window compresses).
//    Safety: any overwrite of the parity being read is gated behind a poll
//    that transitively includes this block's own prog (B3 joins all waves).
//  * bi-row AdjL rebuild moved from the single r==bi thread (serial 16 reads
//    + 8 writes) to wave8 lanes 0..7 (8-wide, waves 8-14 were idle in E+D).
//    Only thread r ever writes AdjL row r otherwise -> no race; B5 orders
//    the rebuild before rescans.
//  * thread r==bi keeps only bookkeeping (rescanList, SIl/SJl, tp).
__global__ void __launch_bounds__(cT, 4)
parse_main(const float* __restrict__ W1, const float* __restrict__ b1,
           char* __restrict__ ws, float* __restrict__ out) {
    const int t  = threadIdx.x;           // 0..1023
    const int b  = blockIdx.x & 15;       // batch (blocks of a batch share an XCD)
    const int g  = blockIdx.x >> 4;       // 0..7
    const int d0 = g * 64;
    const int wf = t >> 6;                // wave id 0..15
    const int ln = t & 63;
    const int wv = wf >> 1;               // k-chunk 0..7
    const int h  = wf & 1;                // half: 0 -> even-pair k, 1 -> odd-pair k

    unsigned long long* F64[2] = {
        (unsigned long long*)(ws + OFF_F0) + (size_t)b * cS * cD / 2,
        (unsigned long long*)(ws + OFF_F1) + (size_t)b * cS * cD / 2 };
    unsigned* prog = (unsigned*)(ws + OFF_BAR) + (size_t)b * 256;   // counters at prog[g*32]
    const float* SCp = (const float*)(ws + OFF_SC);
    const float c0 = SCp[0], cu_c = SCp[1], cv_c = SCp[2];

    // replicated per-block state
    __shared__ unsigned long long AdjL[8 * 512];   // column-major: AdjL[w*512 + r]
    __shared__ float SIl[512], SJl[512], rmax[512];
    __shared__ int   rarg[512];
    __shared__ int   tp[512];                      // (tau<<1) | par
    __shared__ float rsh[1024];
    __shared__ float ws_si[8], ws_sj[8];
    __shared__ int   s_info;                       // bi | bj<<9
    __shared__ int   rescanList[516]; __shared__ int nresc;
    __shared__ int   iterLog[512];                 // bi|bj<<9 per iteration

    // W1 slice: thread (wf,ln) holds 64 k's of chunk wv (h selects pair parity)
    const int kbase = wv * 128;
    float2 wreg2[32];
#pragma unroll
    for (int m = 0; m < 32; m++) {
        wreg2[m].x = W1[(size_t)(kbase + 4 * m + 2 * h)     * cD + d0 + ln];
        wreg2[m].y = W1[(size_t)(kbase + 4 * m + 2 * h + 1) * cD + d0 + ln];
    }

    // csi/csj constants (h==0 waves only; they see chunk dims (2ln, 2ln+1))
    const int xk = (wv & 3) * 128 + 2 * ln;
    float cu0 = 0.f, cu1 = 0.f, cv0 = 0.f, cv1 = 0.f;
    if (h == 0) {
        const float* cu_base = (const float*)(ws + ((wv < 4) ? OFF_UA : OFF_UB));
        const float* cvb     = (const float*)(ws + ((wv < 4) ? OFF_VA : OFF_VB));
        cu0 = cu_base[xk]; cu1 = cu_base[xk + 1];
        cv0 = cvb[xk];     cv1 = cvb[xk + 1];
    }

    // replicated init (rows live in t<512)
    if (t < cS) {
        SIl[t]  = ((const float*)(ws + OFF_SI))[b * cS + t];
        SJl[t]  = ((const float*)(ws + OFF_SJ))[b * cS + t];
        rmax[t] = ((const float*)(ws + OFF_RM))[b * cS + t];
        rarg[t] = ((const int*)(ws + OFF_RA))[b * cS + t];
        tp[t]   = -2;                    // tau=-1, par=0
        const unsigned long long* AG =
            (const unsigned long long*)(ws + OFF_ADJ) + (size_t)b * cS * 8;
#pragma unroll
        for (int wq = 0; wq < 8; wq++) AdjL[wq * 512 + t] = AG[(size_t)t * 8 + wq];
    }
    float b1v = 0.f;
    if (wf == 15) b1v = b1[d0 + ln];       // storer wave: one output dim per lane
    bool myAlive = true;
    float tot = 0.f;
    int minp = 0;                          // per-thread proven lower bound (own 2 producers)
    if (t == 0) nresc = 0;
    __syncthreads();   // init barrier

    for (int it = 0; it < cS - 1; ++it) {
        // ---- A: wave0 pure argmax over rmax/rarg ----
        if (wf == 0) {
            float v0[8]; int k0[8];
#pragma unroll
            for (int k = 0; k < 8; k++) {
                const int r = k * 64 + ln;
                v0[k] = rmax[r];
                k0[k] = (r << 9) | (rarg[r] & 511);
            }
            vk_max(v0[0], k0[0], v0[1], k0[1]);
            vk_max(v0[2], k0[2], v0[3], k0[3]);
            vk_max(v0[4], k0[4], v0[5], k0[5]);
            vk_max(v0[6], k0[6], v0[7], k0[7]);
            vk_max(v0[0], k0[0], v0[2], k0[2]);
            vk_max(v0[4], k0[4], v0[6], k0[6]);
            vk_max(v0[0], k0[0], v0[4], k0[4]);
            float bv = v0[0]; int bk = k0[0];
            wave_max64(bv, bk);            // result in lane 63
            const int bk63 = __builtin_amdgcn_readlane(bk, 63);
            const int pbi = bk63 >> 9, pbj = bk63 & 511;
            if (ln == 0) {
                const int info0 = pbi | (pbj << 9);
                s_info = info0;
                iterLog[it] = info0;
                nresc = 0;
                if (g == 0) {
                    tot += __int_as_float(
                        __builtin_amdgcn_readlane(__float_as_int(bv), 63));
                }
            }
        }
        __syncthreads();   // B2
        const int info = s_info;
        const int bi = info & 511, bj = (info >> 9) & 511;

        // ---- C: per-wave 2-producer poll + load + csi/csj + readlane matvec ----
        const int myrow = (wv < 4) ? bi : bj;
        const int tpr   = tp[myrow];               // wave-uniform LDS read
        const int mypar = tpr & 1;
        const int need  = (tpr >> 1) + 1;          // tau=-1 -> need=0 (skip)
        int pari = 0;
        if (wf == 15) pari = tp[bi] & 1;           // store-target parity (old)
        if (need > minp) {
            // quarter (wv&3) is produced by blocks 2*(wv&3) and 2*(wv&3)+1 only
            const int gq = 2 * (wv & 3);
            const unsigned un = (unsigned)need;
            for (;;) {
                unsigned v = 0xffffffffu;
                if (ln < 2) v = __hip_atomic_load(prog + (gq + ln) * 32, __ATOMIC_RELAXED,
                                                  __HIP_MEMORY_SCOPE_AGENT);
                if (__ballot(v >= un) == ~0ull) break;
                __builtin_amdgcn_s_sleep(1);
            }
            minp = need;
        }
        unsigned long long xv = __hip_atomic_load(
            F64[mypar] + (size_t)myrow * 256 + (wv & 3) * 64 + ln,
            __ATOMIC_RELAXED, __HIP_MEMORY_SCOPE_AGENT);
        float2 f2; __builtin_memcpy(&f2, &xv, 8);
        // csi/csj partials (h==0 waves; same tree -> bit-exact)
        if (h == 0) {
            float csi = f2.x * cu0 + f2.y * cu1;
            float csj = f2.x * cv0 + f2.y * cv1;
            csi += __shfl_down(csi, 32, 64);  csj += __shfl_down(csj, 32, 64);
            csi += __shfl_down(csi, 16, 64);  csj += __shfl_down(csj, 16, 64);
            csi = dpp_shl_add<8>(csi);  csj = dpp_shl_add<8>(csj);
            csi = dpp_shl_add<4>(csi);  csj = dpp_shl_add<4>(csj);
            csi = dpp_shl_add<2>(csi);  csj = dpp_shl_add<2>(csj);
            csi = dpp_shl_add<1>(csi);  csj = dpp_shl_add<1>(csj);
            if (ln == 0) { ws_si[wv] = csi; ws_sj[wv] = csj; }
        }
        // matvec: h branched out -> readlane lane is a compile-time immediate.
        {
            const int ix = __float_as_int(f2.x), iy = __float_as_int(f2.y);
            float aP = 0.f, aQ = 0.f;
            if (h == 0) {
#pragma unroll
                for (int m = 0; m < 32; m++) {
                    const float q0 = __int_as_float(__builtin_amdgcn_readlane(ix, 2 * m));
                    const float q1 = __int_as_float(__builtin_amdgcn_readlane(iy, 2 * m));
                    aP = fmaf(wreg2[m].x, q0, aP);
                    aQ = fmaf(wreg2[m].y, q1, aQ);
                }
            } else {
#pragma unroll
                for (int m = 0; m < 32; m++) {
                    const float q0 = __int_as_float(__builtin_amdgcn_readlane(ix, 2 * m + 1));
                    const float q1 = __int_as_float(__builtin_amdgcn_readlane(iy, 2 * m + 1));
                    aP = fmaf(wreg2[m].x, q0, aP);
                    aQ = fmaf(wreg2[m].y, q1, aQ);
                }
            }
            rsh[t] = aP + aQ;   // h=0: a0+a1, h=1: a2+a3
        }
        __syncthreads();   // B3

        if (wf == 15) {
            // ---- S: gather + store + drain + publish (earliest possible) ----
            float p = b1v;
#pragma unroll
            for (int q = 0; q < 8; q++)
                p += rsh[(2 * q) * 64 + ln] + rsh[(2 * q + 1) * 64 + ln];
            // ((b1+P0)+P1)... with P_q = (a0+a1)+(a2+a3): identical tree
            __hip_atomic_store((float*)F64[pari ^ 1] + (size_t)bi * 512 + d0 + ln, p,
                               __ATOMIC_RELAXED, __HIP_MEMORY_SCOPE_AGENT);
            asm volatile("s_waitcnt vmcnt(0)" ::: "memory");
            if (ln == 0)
                __hip_atomic_store(prog + g * 32, (unsigned)(it + 1), __ATOMIC_RELAXED,
                                   __HIP_MEMORY_SCOPE_AGENT);
        } else if (wf == 8) {
            // ---- bi-row rebuild, 8-wide (was serial on thread r==bi) ----
            if (ln < 8) {
                const int wq = ln;
                const int wbi = bi >> 6, wbj = bj >> 6;
                const unsigned long long mbi = 1ull << (bi & 63), mbj = 1ull << (bj & 63);
                unsigned long long nw = AdjL[wq * 512 + bi] | AdjL[wq * 512 + bj];
                if (wq == wbi) nw &= ~mbi;
                if (wq == wbj) nw &= ~mbj;
                AdjL[wq * 512 + bi] = nw;
            }
        } else if (t < cS) {
            // ---- E: replicated sin/sjn (same tree -> bit-exact) ----
            float su = (ln < 8) ? ws_si[ln] : 0.f;
            float sv = (ln < 8) ? ws_sj[ln] : 0.f;
            su = dpp_shl_add<4>(su);  sv = dpp_shl_add<4>(sv);
            su = dpp_shl_add<2>(su);  sv = dpp_shl_add<2>(sv);
            su = dpp_shl_add<1>(su);  sv = dpp_shl_add<1>(sv);
            const float sn = __int_as_float(
                __builtin_amdgcn_readfirstlane(__float_as_int(su))) + cu_c;
            const float jn = __int_as_float(
                __builtin_amdgcn_readfirstlane(__float_as_int(sv))) + cv_c;

            // ---- D: adjacency + incremental rowmax (LDS only) ----
            const float sjn_ = jn;
            const int wbi = bi >> 6, wbj = bj >> 6;
            const unsigned long long mbi = 1ull << (bi & 63), mbj = 1ull << (bj & 63);
            const int r = t;
            if (r == bj) {
                if (myAlive) { myAlive = false; rmax[t] = -INFINITY; }
            } else if (r == bi) {
                // row rebuild now done by wave8; bookkeeping only
                int slot = atomicAdd(&nresc, 1); rescanList[slot] = bi;
                SIl[bi] = sn; SJl[bi] = jn;
                tp[bi] = (it << 1) | ((tp[bi] & 1) ^ 1);
            } else if (myAlive) {
                unsigned long long wi = AdjL[wbi * 512 + r];
                unsigned long long wj = (wbj == wbi) ? wi : AdjL[wbj * 512 + r];
                const bool nb = ((wi & mbi) | (wj & mbj)) != 0ull;
                if (wbi == wbj) {
                    AdjL[wbi * 512 + r] = (wi & ~(mbi | mbj)) | (nb ? mbi : 0ull);
                } else {
                    AdjL[wbi * 512 + r] = (wi & ~mbi) | (nb ? mbi : 0ull);
                    AdjL[wbj * 512 + r] = wj & ~mbj;
                }
                const int ra = rarg[t];
                if (ra == bi || ra == bj) {
                    int slot = atomicAdd(&nresc, 1); rescanList[slot] = r;
                } else if (nb) {
                    const float val = SIl[r] + sjn_ + c0;
                    if (val > rmax[t] || (val == rmax[t] && bi < ra)) { rmax[t] = val; rarg[t] = bi; }
                }
            }
        }
        __syncthreads();   // B5

        // ---- wave-parallel rescans (DPP reduce, result lane 63) ----
        const int nr = nresc;
        for (int q = wf; q < nr; q += 16) {
            const int r = rescanList[q];
            const float sir = SIl[r];
            float bv2 = -INFINITY; int bc2 = 0x7fffffff;
#pragma unroll
            for (int k = 0; k < 8; k++) {
                const unsigned long long word = AdjL[k * 512 + r];   // wave-uniform
                if ((word >> ln) & 1ull) {
                    const int c = k * 64 + ln;
                    const float val = sir + SJl[c] + c0;
                    if (val > bv2 || (val == bv2 && c < bc2)) { bv2 = val; bc2 = c; }
                }
            }
            wave_max64(bv2, bc2);
            if (ln == 63) { rmax[r] = bv2; rarg[r] = bc2; }
        }
        __syncthreads();   // B6
    }

    // ---- final writeback: parse tree from iterLog + total score ----
    __syncthreads();
    if (g == 0) {
        if (t < 2 * (cS - 1)) {
            const int e = iterLog[t >> 1];
            const int val = (t & 1) ? ((e >> 9) & 511) : (e & 511);
            out[16 + b * 1022 + t] = (float)val;
        }
        if (t == 0) out[b] = tot;
    }
}

extern "C" void kernel_launch(void* const* d_in, const int* in_sizes, int n_in,
                              void* d_out, int out_size, void* d_ws, size_t ws_size,
                              hipStream_t stream) {
    const int*   token_ids = (const int*)d_in[0];
    const float* vocab_emb = (const float*)d_in[1];
    const float* pos_W     = (const float*)d_in[2];
    const float* pos_b     = (const float*)d_in[3];
    const float* W1        = (const float*)d_in[4];
    const float* b1        = (const float*)d_in[5];
    const float* w2        = (const float*)d_in[6];
    const float* b2        = (const float*)d_in[7];
    float* out = (float*)d_out;
    char*  ws  = (char*)d_ws;

    k1_uvc<<<1026, 256, 0, stream>>>(W1, b1, w2, b2, ws);
    k1b_proj<<<1025, 256, 0, stream>>>(W1, b1, ws);
    k2_feat<<<cB * cS, 256, 0, stream>>>(token_ids, vocab_emb, ws);
    k3_cls<<<cB * cS, 64, 0, stream>>>(pos_W, pos_b, ws);
    k4_adj<<<cB * cS, 256, 0, stream>>>(ws);

    // cooperative launch for the co-residency guarantee (custom waits inside)
    void* args[] = { (void*)&W1, (void*)&b1, (void*)&ws, (void*)&out };
    hipLaunchCooperativeKernel((void*)parse_main, dim3(cB * cG), dim3(cT),
                               args, 0, stream);
}